// Round 1
// 328.445 us; speedup vs baseline: 1.1054x; 1.1054x over previous
//
#include <hip/hip_runtime.h>

#define NN 100000
#define NE 1600000
#define NBUK 1563          // ceil(NN/64) buckets of 64 nodes
#define EB 8192            // edges per scatter block

typedef __attribute__((ext_vector_type(8))) short v8s;
typedef __attribute__((ext_vector_type(4))) float v4f;

__device__ __forceinline__ unsigned short f2bf(float f) {
  unsigned int u = __float_as_uint(f);
  unsigned int r = (u + 0x7FFFu + ((u >> 16) & 1u)) >> 16;
  return (unsigned short)r;
}
__device__ __forceinline__ float bflo(unsigned int w) { return __uint_as_float(w << 16); }
__device__ __forceinline__ float bfhi(unsigned int w) { return __uint_as_float(w & 0xFFFF0000u); }
__device__ __forceinline__ float bf2f(unsigned short w) {
  return __uint_as_float((unsigned int)w << 16);
}

// ---------------- bucket histogram ----------------

__global__ void k_zerob(int* __restrict__ hist) {
  int i = blockIdx.x * blockDim.x + threadIdx.x;
  if (i < NBUK) hist[i] = 0;
}

__global__ __launch_bounds__(256) void k_hist(const int* __restrict__ dst,
                                              int* __restrict__ hist) {
  __shared__ int lh[NBUK];
  int t = threadIdx.x;
  for (int i = t; i < NBUK; i += 256) lh[i] = 0;
  __syncthreads();
  int base = blockIdx.x * 16384;
  int lim = min(16384, NE - base);
  for (int j = t; j < lim; j += 256) atomicAdd(&lh[dst[base + j] >> 6], 1);
  __syncthreads();
  for (int i = t; i < NBUK; i += 256) {
    int c = lh[i];
    if (c) atomicAdd(&hist[i], c);
  }
}

// single-block chunked exclusive scan: hist -> bbase, gcur
__global__ __launch_bounds__(256) void k_scanb(const int* __restrict__ hist,
                                               int* __restrict__ bbase,
                                               int* __restrict__ gcur) {
  __shared__ int sc[256];
  __shared__ int carry;
  int t = threadIdx.x;
  if (t == 0) carry = 0;
  __syncthreads();
  for (int c = 0; c < (NBUK + 255) / 256; ++c) {
    int i = c * 256 + t;
    int vv = (i < NBUK) ? hist[i] : 0;
    sc[t] = vv;
    __syncthreads();
    for (int o = 1; o < 256; o <<= 1) {
      int uu = (t >= o) ? sc[t - o] : 0;
      __syncthreads();
      sc[t] += uu;
      __syncthreads();
    }
    int excl = carry + sc[t] - vv;
    if (i < NBUK) { bbase[i] = excl; gcur[i] = excl; }
    __syncthreads();
    if (t == 0) carry += sc[255];
    __syncthreads();
  }
}

// ---------------- LDS-staged bucket scatter (linear global writes) ---------
// staged[k] = (src<<6) | dstLocal, bucket-sorted.
extern __shared__ char smem_dyn[];
__global__ __launch_bounds__(256) void k_scatter(const int* __restrict__ src,
                                                 const int* __restrict__ dst,
                                                 int* __restrict__ gcur,
                                                 unsigned int* __restrict__ staged) {
  unsigned int* stageP = (unsigned int*)smem_dyn;              // EB
  unsigned short* stageB = (unsigned short*)(stageP + EB);     // EB
  int* lhist  = (int*)(stageB + EB);                           // NBUK
  int* lbase  = lhist + NBUK;
  int* lcur   = lbase + NBUK;
  int* gclaim = lcur + NBUK;
  __shared__ int sc[256];
  __shared__ int carry;
  int t = threadIdx.x;
  int e0 = blockIdx.x * EB;
  int ecnt = min(EB, NE - e0);
  for (int i = t; i < NBUK; i += 256) lhist[i] = 0;
  if (t == 0) carry = 0;
  __syncthreads();
  for (int j = t; j < ecnt; j += 256) atomicAdd(&lhist[dst[e0 + j] >> 6], 1);
  __syncthreads();
  for (int c = 0; c < (NBUK + 255) / 256; ++c) {
    int i = c * 256 + t;
    int vv = (i < NBUK) ? lhist[i] : 0;
    sc[t] = vv;
    __syncthreads();
    for (int o = 1; o < 256; o <<= 1) {
      int uu = (t >= o) ? sc[t - o] : 0;
      __syncthreads();
      sc[t] += uu;
      __syncthreads();
    }
    int excl = carry + sc[t] - vv;
    if (i < NBUK) { lbase[i] = excl; lcur[i] = excl; }
    __syncthreads();
    if (t == 0) carry += sc[255];
    __syncthreads();
  }
  for (int b = t; b < NBUK; b += 256) {
    int c = lhist[b];
    gclaim[b] = c ? atomicAdd(&gcur[b], c) : 0;
  }
  __syncthreads();
  for (int j = t; j < ecnt; j += 256) {
    int s = src[e0 + j], d = dst[e0 + j];
    int b = d >> 6;
    int lp = atomicAdd(&lcur[b], 1);
    stageP[lp] = ((unsigned int)s << 6) | (unsigned int)(d & 63);
    stageB[lp] = (unsigned short)b;
  }
  __syncthreads();
  for (int i = t; i < ecnt; i += 256) {
    int b = stageB[i];
    staged[gclaim[b] + (i - lbase[b])] = stageP[i];
  }
}

// ---------------- per-bucket radix pass 2: staged -> CSR + off + deg -------
// Writes land only within the bucket's contiguous window (no write amp).
__global__ __launch_bounds__(256) void k_sort2(const unsigned int* __restrict__ staged,
                                               const int* __restrict__ bbase,
                                               const int* __restrict__ hist,
                                               int* __restrict__ csr,
                                               int* __restrict__ off,
                                               int* __restrict__ deg) {
  __shared__ int h64[64], c64[64];
  int bkt = blockIdx.x, t = threadIdx.x;
  if (t < 64) h64[t] = 0;
  __syncthreads();
  int st = bbase[bkt], cnt = hist[bkt];
  for (int j = t; j < cnt; j += 256) atomicAdd(&h64[staged[st + j] & 63], 1);
  __syncthreads();
  if (t < 64) {
    int v = h64[t];
    int inc = v;
    for (int o = 1; o < 64; o <<= 1) {
      int uu = __shfl_up(inc, o, 64);
      if (t >= o) inc += uu;
    }
    int excl = inc - v;
    c64[t] = excl;
    int node = bkt * 64 + t;
    if (node < NN) { off[node] = st + excl; deg[node] = v; }
  }
  __syncthreads();
  for (int j = t; j < cnt; j += 256) {
    unsigned pk = staged[st + j];
    int lp = atomicAdd(&c64[pk & 63], 1);
    csr[st + lp] = (int)(pk >> 6);
  }
}

// ---------------- weight pack ----------------

__global__ void k_packw(const float* __restrict__ W1l, const float* __restrict__ W1r,
                        unsigned short* __restrict__ Wcat) {
  int i = blockIdx.x * blockDim.x + threadIdx.x;  // 0..32767
  float f = (i < 16384) ? W1l[i] : W1r[i - 16384];
  Wcat[i] = f2bf(f);
}

// ---------------- MFMA GEMM: u = x@W1l^T, v = x@W1r^T (bf16 out) ----------
__global__ __launch_bounds__(256) void k_gemm1(
    const float* __restrict__ x, const unsigned short* __restrict__ Wcat,
    unsigned short* __restrict__ u, unsigned short* __restrict__ v) {
  int wave = threadIdx.x >> 6, l = threadIdx.x & 63;
  int m0 = blockIdx.x * 64 + wave * 16;
  if (m0 >= NN) return;
  int lr = l & 15, kq = l >> 4;
  int rowc = min(m0 + lr, NN - 1);

  v8s a[4];
#pragma unroll
  for (int ks = 0; ks < 4; ++ks) {
    const float* xp = x + (size_t)rowc * 128 + ks * 32 + kq * 8;
    float4 f0 = *(const float4*)xp;
    float4 f1 = *(const float4*)(xp + 4);
    v8s tv;
    tv[0] = (short)f2bf(f0.x); tv[1] = (short)f2bf(f0.y);
    tv[2] = (short)f2bf(f0.z); tv[3] = (short)f2bf(f0.w);
    tv[4] = (short)f2bf(f1.x); tv[5] = (short)f2bf(f1.y);
    tv[6] = (short)f2bf(f1.z); tv[7] = (short)f2bf(f1.w);
    a[ks] = tv;
  }

  v4f acc[16];
#pragma unroll
  for (int nt = 0; nt < 16; ++nt) acc[nt] = (v4f){0.f, 0.f, 0.f, 0.f};

#pragma unroll
  for (int nt = 0; nt < 16; ++nt) {
    const unsigned short* wrow = Wcat + (size_t)(nt * 16 + lr) * 128;
#pragma unroll
    for (int ks = 0; ks < 4; ++ks) {
      v8s b = *(const v8s*)(wrow + ks * 32 + kq * 8);
      acc[nt] = __builtin_amdgcn_mfma_f32_16x16x32_bf16(a[ks], b, acc[nt], 0, 0, 0);
    }
  }

#pragma unroll
  for (int nt = 0; nt < 16; ++nt) {
#pragma unroll
    for (int rr = 0; rr < 4; ++rr) {
      int mrow = m0 + kq * 4 + rr;
      if (mrow < NN) {
        unsigned short bv = f2bf(acc[nt][rr]);
        int col = nt * 16 + lr;
        if (nt < 8) u[(size_t)mrow * 128 + col] = bv;
        else        v[(size_t)mrow * 128 + (col - 128)] = bv;
      }
    }
  }
}

// ---------------- fused: mean-agg(u) + v + b1 -> relu -> h1; p=h1@W2l^T,
//                  r=h1@W2r^T.
// One wave per node. Lane layout: half = l>>5 selects which edge of a PAIR,
// dpos = l&31 covers dims 4*dpos..4*dpos+3 via one dwordx2 (4 bf16) load.
// Wave processes 2 edges per load instruction; per-edge VALU ~6 ops vs ~20
// in the 1-dword-per-lane version. Edge ids bulk-loaded (coalesced, 64 at a
// time) and distributed via __shfl (ds_bpermute, 1 instr).
__global__ __launch_bounds__(256) void k_agg(
    const unsigned short* __restrict__ u, const unsigned short* __restrict__ v,
    const int* __restrict__ csr, const int* __restrict__ off, const int* __restrict__ deg,
    const float* __restrict__ b1,
    const float* __restrict__ W2l, const float* __restrict__ W2r,
    float* __restrict__ p, float* __restrict__ r) {
  int wid = (blockIdx.x * blockDim.x + threadIdx.x) >> 6;  // node
  int l = threadIdx.x & 63;
  if (wid >= NN) return;
  int cnt = deg[wid], st = off[wid];
  int half = l >> 5;
  int dpos = l & 31;
  const char* ubase = (const char*)u + (dpos << 3);

  float a0 = 0.f, a1 = 0.f, a2 = 0.f, a3 = 0.f;

#define LOADW(W, S) uint2 W = *(const uint2*)(ubase + ((size_t)((unsigned)(S) << 8)))
#define ACCW(W) { a0 += bflo(W.x); a1 += bfhi(W.x); a2 += bflo(W.y); a3 += bfhi(W.y); }

  for (int base = 0; base < cnt; base += 64) {
    int nloc = min(64, cnt - base);
    int idx = 0;
    if (l < nloc) idx = csr[st + base + l];
    int npair = nloc >> 1;
    int e = 0;
    for (; e + 4 <= npair; e += 4) {
      int s0 = __shfl(idx, 2 * e + half, 64);
      int s1 = __shfl(idx, 2 * (e + 1) + half, 64);
      int s2 = __shfl(idx, 2 * (e + 2) + half, 64);
      int s3 = __shfl(idx, 2 * (e + 3) + half, 64);
      LOADW(w0, s0);
      LOADW(w1, s1);
      LOADW(w2, s2);
      LOADW(w3, s3);
      ACCW(w0); ACCW(w1); ACCW(w2); ACCW(w3);
    }
    for (; e < npair; ++e) {
      int s = __shfl(idx, 2 * e + half, 64);
      LOADW(w, s);
      ACCW(w);
    }
    if (nloc & 1) {
      int s = __shfl(idx, nloc - 1, 64);
      if (half == 0) {
        LOADW(w, s);
        ACCW(w);
      }
    }
  }
#undef LOADW
#undef ACCW

  // merge the two edge-halves; afterwards both halves hold full sums
  a0 += __shfl_xor(a0, 32, 64);
  a1 += __shfl_xor(a1, 32, 64);
  a2 += __shfl_xor(a2, 32, 64);
  a3 += __shfl_xor(a3, 32, 64);

  float inv = 1.f / (float)max(cnt, 1);
  uint2 vw = *(const uint2*)((const char*)v + ((size_t)wid << 8) + (dpos << 3));
  float4 bb = *(const float4*)(b1 + 4 * dpos);
  float h0 = fmaxf(fmaf(a0, inv, bflo(vw.x) + bb.x), 0.f);
  float h1 = fmaxf(fmaf(a1, inv, bfhi(vw.x) + bb.y), 0.f);
  float h2 = fmaxf(fmaf(a2, inv, bflo(vw.y) + bb.z), 0.f);
  float h3 = fmaxf(fmaf(a3, inv, bfhi(vw.y) + bb.w), 0.f);

  // half 0 -> p = h@W2l^T ; half 1 -> r = h@W2r^T  (4 outputs each)
  const float* Wbase = half ? W2r : W2l;
  float* outp = half ? r : p;
#pragma unroll
  for (int o = 0; o < 4; ++o) {
    float4 wv = *(const float4*)(Wbase + o * 128 + 4 * dpos);
    float s = h0 * wv.x + h1 * wv.y + h2 * wv.z + h3 * wv.w;
#pragma unroll
    for (int d = 16; d > 0; d >>= 1) s += __shfl_xor(s, d, 64);  // stays in half
    if (dpos == o) outp[(size_t)wid * 4 + o] = s;
  }
}

// ---------------- layer-2 aggregation (4-wide) + final linear ----------------
__global__ void k_final(const float* __restrict__ p, const float* __restrict__ r,
                        const int* __restrict__ csr, const int* __restrict__ off,
                        const int* __restrict__ deg,
                        const float* __restrict__ b2,
                        const float* __restrict__ Wlin, const float* __restrict__ blin,
                        float* __restrict__ out) {
  int i = blockIdx.x * blockDim.x + threadIdx.x;
  if (i >= NN) return;
  int cnt = deg[i], st = off[i];
  float a0 = 0.f, a1 = 0.f, a2 = 0.f, a3 = 0.f;
  for (int e = 0; e < cnt; ++e) {
    int s = csr[st + e];
    const float4 pv = *(const float4*)(p + (size_t)s * 4);
    a0 += pv.x; a1 += pv.y; a2 += pv.z; a3 += pv.w;
  }
  float inv = 1.f / (float)max(cnt, 1);
  float4 rv = *(const float4*)(r + (size_t)i * 4);
  float g0 = a0 * inv + b2[0] + rv.x;
  float g1 = a1 * inv + b2[1] + rv.y;
  float g2 = a2 * inv + b2[2] + rv.z;
  float g3 = a3 * inv + b2[3] + rv.w;
  out[(size_t)i * 2 + 0] = g0 * Wlin[0] + g1 * Wlin[1] + g2 * Wlin[2] + g3 * Wlin[3] + blin[0];
  out[(size_t)i * 2 + 1] = g0 * Wlin[4] + g1 * Wlin[5] + g2 * Wlin[6] + g3 * Wlin[7] + blin[1];
}

// ---------------- launch ----------------

extern "C" void kernel_launch(void* const* d_in, const int* in_sizes, int n_in,
                              void* d_out, int out_size, void* d_ws, size_t ws_size,
                              hipStream_t stream) {
  const float* x    = (const float*)d_in[0];
  const int*   ei   = (const int*)d_in[1];
  const int*   src  = ei;
  const int*   dst  = ei + NE;
  const float* W1l  = (const float*)d_in[2];
  const float* b1   = (const float*)d_in[3];
  const float* W1r  = (const float*)d_in[4];
  const float* W2l  = (const float*)d_in[5];
  const float* b2   = (const float*)d_in[6];
  const float* W2r  = (const float*)d_in[7];
  const float* Wlin = (const float*)d_in[8];
  const float* blin = (const float*)d_in[9];
  float* out = (float*)d_out;

  char* w = (char*)d_ws;
  size_t o = 0;
  auto alloc = [&](size_t bytes) {
    void* pp = (void*)(w + o);
    o = (o + bytes + 255) & ~(size_t)255;
    return pp;
  };
  int* hist  = (int*)alloc(NBUK * 4);
  int* bbase = (int*)alloc(NBUK * 4);
  int* gcur  = (int*)alloc(NBUK * 4);
  unsigned int*  staged = (unsigned int*)alloc((size_t)NE * 4);
  int* csr   = (int*)alloc((size_t)NE * 4);
  int* offs  = (int*)alloc(NN * 4);
  int* deg   = (int*)alloc(NN * 4);
  unsigned short* Wcat  = (unsigned short*)alloc(256 * 128 * 2);
  unsigned short* ubuf  = (unsigned short*)alloc((size_t)NN * 128 * 2);
  unsigned short* vbuf  = (unsigned short*)alloc((size_t)NN * 128 * 2);
  float* pbuf = (float*)alloc((size_t)NN * 4 * 4);
  float* rbuf = (float*)alloc((size_t)NN * 4 * 4);

  const size_t scatter_lds = (size_t)EB * 4 + (size_t)EB * 2 + (size_t)4 * NBUK * 4;

  hipLaunchKernelGGL(k_zerob, dim3((NBUK + 255) / 256), dim3(256), 0, stream, hist);
  hipLaunchKernelGGL(k_hist,  dim3((NE + 16383) / 16384), dim3(256), 0, stream, dst, hist);
  hipLaunchKernelGGL(k_scanb, dim3(1), dim3(256), 0, stream, hist, bbase, gcur);
  hipLaunchKernelGGL(k_scatter, dim3((NE + EB - 1) / EB), dim3(256), scatter_lds, stream,
                     src, dst, gcur, staged);
  hipLaunchKernelGGL(k_sort2, dim3(NBUK), dim3(256), 0, stream,
                     staged, bbase, hist, csr, offs, deg);
  hipLaunchKernelGGL(k_packw, dim3(128), dim3(256), 0, stream, W1l, W1r, Wcat);
  hipLaunchKernelGGL(k_gemm1, dim3((NN + 63) / 64), dim3(256), 0, stream, x, Wcat, ubuf, vbuf);
  hipLaunchKernelGGL(k_agg,   dim3((NN * 64 + 255) / 256), dim3(256), 0, stream,
                     ubuf, vbuf, csr, offs, deg, b1, W2l, W2r, pbuf, rbuf);
  hipLaunchKernelGGL(k_final, dim3((NN + 255) / 256), dim3(256), 0, stream,
                     pbuf, rbuf, csr, offs, deg, b2, Wlin, blin, out);
}

// Round 4
// 324.814 us; speedup vs baseline: 1.1177x; 1.0112x over previous
//
#include <hip/hip_runtime.h>

#define NN 100000
#define NE 1600000
#define NBUK 1563          // ceil(NN/64) buckets of 64 nodes
#define EB 8192            // edges per scatter block

typedef __attribute__((ext_vector_type(8))) short v8s;
typedef __attribute__((ext_vector_type(4))) float v4f;

__device__ __forceinline__ unsigned short f2bf(float f) {
  unsigned int u = __float_as_uint(f);
  unsigned int r = (u + 0x7FFFu + ((u >> 16) & 1u)) >> 16;
  return (unsigned short)r;
}
__device__ __forceinline__ float bflo(unsigned int w) { return __uint_as_float(w << 16); }
__device__ __forceinline__ float bfhi(unsigned int w) { return __uint_as_float(w & 0xFFFF0000u); }
__device__ __forceinline__ float bf2f(unsigned short w) {
  return __uint_as_float((unsigned int)w << 16);
}

// ---------------- bucket histogram ----------------

__global__ void k_zerob(int* __restrict__ hist) {
  int i = blockIdx.x * blockDim.x + threadIdx.x;
  if (i < NBUK) hist[i] = 0;
}

__global__ __launch_bounds__(256) void k_hist(const int* __restrict__ dst,
                                              int* __restrict__ hist) {
  __shared__ int lh[NBUK];
  int t = threadIdx.x;
  for (int i = t; i < NBUK; i += 256) lh[i] = 0;
  __syncthreads();
  int base = blockIdx.x * 16384;
  int lim = min(16384, NE - base);
  for (int j = t; j < lim; j += 256) atomicAdd(&lh[dst[base + j] >> 6], 1);
  __syncthreads();
  for (int i = t; i < NBUK; i += 256) {
    int c = lh[i];
    if (c) atomicAdd(&hist[i], c);
  }
}

// single-block chunked exclusive scan: hist -> bbase, gcur
__global__ __launch_bounds__(256) void k_scanb(const int* __restrict__ hist,
                                               int* __restrict__ bbase,
                                               int* __restrict__ gcur) {
  __shared__ int sc[256];
  __shared__ int carry;
  int t = threadIdx.x;
  if (t == 0) carry = 0;
  __syncthreads();
  for (int c = 0; c < (NBUK + 255) / 256; ++c) {
    int i = c * 256 + t;
    int vv = (i < NBUK) ? hist[i] : 0;
    sc[t] = vv;
    __syncthreads();
    for (int o = 1; o < 256; o <<= 1) {
      int uu = (t >= o) ? sc[t - o] : 0;
      __syncthreads();
      sc[t] += uu;
      __syncthreads();
    }
    int excl = carry + sc[t] - vv;
    if (i < NBUK) { bbase[i] = excl; gcur[i] = excl; }
    __syncthreads();
    if (t == 0) carry += sc[255];
    __syncthreads();
  }
}

// ---------------- LDS-staged bucket scatter (linear global writes) ---------
// staged[k] = (src<<6) | dstLocal, bucket-sorted.
extern __shared__ char smem_dyn[];
__global__ __launch_bounds__(256) void k_scatter(const int* __restrict__ src,
                                                 const int* __restrict__ dst,
                                                 int* __restrict__ gcur,
                                                 unsigned int* __restrict__ staged) {
  unsigned int* stageP = (unsigned int*)smem_dyn;              // EB
  unsigned short* stageB = (unsigned short*)(stageP + EB);     // EB
  int* lhist  = (int*)(stageB + EB);                           // NBUK
  int* lbase  = lhist + NBUK;
  int* lcur   = lbase + NBUK;
  int* gclaim = lcur + NBUK;
  __shared__ int sc[256];
  __shared__ int carry;
  int t = threadIdx.x;
  int e0 = blockIdx.x * EB;
  int ecnt = min(EB, NE - e0);
  for (int i = t; i < NBUK; i += 256) lhist[i] = 0;
  if (t == 0) carry = 0;
  __syncthreads();
  for (int j = t; j < ecnt; j += 256) atomicAdd(&lhist[dst[e0 + j] >> 6], 1);
  __syncthreads();
  for (int c = 0; c < (NBUK + 255) / 256; ++c) {
    int i = c * 256 + t;
    int vv = (i < NBUK) ? lhist[i] : 0;
    sc[t] = vv;
    __syncthreads();
    for (int o = 1; o < 256; o <<= 1) {
      int uu = (t >= o) ? sc[t - o] : 0;
      __syncthreads();
      sc[t] += uu;
      __syncthreads();
    }
    int excl = carry + sc[t] - vv;
    if (i < NBUK) { lbase[i] = excl; lcur[i] = excl; }
    __syncthreads();
    if (t == 0) carry += sc[255];
    __syncthreads();
  }
  for (int b = t; b < NBUK; b += 256) {
    int c = lhist[b];
    gclaim[b] = c ? atomicAdd(&gcur[b], c) : 0;
  }
  __syncthreads();
  for (int j = t; j < ecnt; j += 256) {
    int s = src[e0 + j], d = dst[e0 + j];
    int b = d >> 6;
    int lp = atomicAdd(&lcur[b], 1);
    stageP[lp] = ((unsigned int)s << 6) | (unsigned int)(d & 63);
    stageB[lp] = (unsigned short)b;
  }
  __syncthreads();
  for (int i = t; i < ecnt; i += 256) {
    int b = stageB[i];
    staged[gclaim[b] + (i - lbase[b])] = stageP[i];
  }
}

// ---------------- per-bucket radix pass 2: staged -> CSR + off + deg -------
__global__ __launch_bounds__(256) void k_sort2(const unsigned int* __restrict__ staged,
                                               const int* __restrict__ bbase,
                                               const int* __restrict__ hist,
                                               int* __restrict__ csr,
                                               int* __restrict__ off,
                                               int* __restrict__ deg) {
  __shared__ int h64[64], c64[64];
  int bkt = blockIdx.x, t = threadIdx.x;
  if (t < 64) h64[t] = 0;
  __syncthreads();
  int st = bbase[bkt], cnt = hist[bkt];
  for (int j = t; j < cnt; j += 256) atomicAdd(&h64[staged[st + j] & 63], 1);
  __syncthreads();
  if (t < 64) {
    int v = h64[t];
    int inc = v;
    for (int o = 1; o < 64; o <<= 1) {
      int uu = __shfl_up(inc, o, 64);
      if (t >= o) inc += uu;
    }
    int excl = inc - v;
    c64[t] = excl;
    int node = bkt * 64 + t;
    if (node < NN) { off[node] = st + excl; deg[node] = v; }
  }
  __syncthreads();
  for (int j = t; j < cnt; j += 256) {
    unsigned pk = staged[st + j];
    int lp = atomicAdd(&c64[pk & 63], 1);
    csr[st + lp] = (int)(pk >> 6);
  }
}

// ---------------- weight pack ----------------

__global__ void k_packw(const float* __restrict__ W1l, const float* __restrict__ W1r,
                        unsigned short* __restrict__ Wcat) {
  int i = blockIdx.x * blockDim.x + threadIdx.x;  // 0..32767
  float f = (i < 16384) ? W1l[i] : W1r[i - 16384];
  Wcat[i] = f2bf(f);
}

// ---------------- MFMA GEMM: u = x@W1l^T, v = x@W1r^T (bf16 out) ----------
__global__ __launch_bounds__(256) void k_gemm1(
    const float* __restrict__ x, const unsigned short* __restrict__ Wcat,
    unsigned short* __restrict__ u, unsigned short* __restrict__ v) {
  int wave = threadIdx.x >> 6, l = threadIdx.x & 63;
  int m0 = blockIdx.x * 64 + wave * 16;
  if (m0 >= NN) return;
  int lr = l & 15, kq = l >> 4;
  int rowc = min(m0 + lr, NN - 1);

  v8s a[4];
#pragma unroll
  for (int ks = 0; ks < 4; ++ks) {
    const float* xp = x + (size_t)rowc * 128 + ks * 32 + kq * 8;
    float4 f0 = *(const float4*)xp;
    float4 f1 = *(const float4*)(xp + 4);
    v8s tv;
    tv[0] = (short)f2bf(f0.x); tv[1] = (short)f2bf(f0.y);
    tv[2] = (short)f2bf(f0.z); tv[3] = (short)f2bf(f0.w);
    tv[4] = (short)f2bf(f1.x); tv[5] = (short)f2bf(f1.y);
    tv[6] = (short)f2bf(f1.z); tv[7] = (short)f2bf(f1.w);
    a[ks] = tv;
  }

  v4f acc[16];
#pragma unroll
  for (int nt = 0; nt < 16; ++nt) acc[nt] = (v4f){0.f, 0.f, 0.f, 0.f};

#pragma unroll
  for (int nt = 0; nt < 16; ++nt) {
    const unsigned short* wrow = Wcat + (size_t)(nt * 16 + lr) * 128;
#pragma unroll
    for (int ks = 0; ks < 4; ++ks) {
      v8s b = *(const v8s*)(wrow + ks * 32 + kq * 8);
      acc[nt] = __builtin_amdgcn_mfma_f32_16x16x32_bf16(a[ks], b, acc[nt], 0, 0, 0);
    }
  }

#pragma unroll
  for (int nt = 0; nt < 16; ++nt) {
#pragma unroll
    for (int rr = 0; rr < 4; ++rr) {
      int mrow = m0 + kq * 4 + rr;
      if (mrow < NN) {
        unsigned short bv = f2bf(acc[nt][rr]);
        int col = nt * 16 + lr;
        if (nt < 8) u[(size_t)mrow * 128 + col] = bv;
        else        v[(size_t)mrow * 128 + (col - 128)] = bv;
      }
    }
  }
}

// ---------------- fused: mean-agg(u) + v + b1 -> relu -> h1; p=h1@W2l^T,
//                  r=h1@W2r^T.
// One wave per node. Lane layout: half = l>>5 selects which edge of a PAIR,
// dpos = l&31 covers dims 4*dpos..4*dpos+3 via one dwordx2 (4 bf16) load.
// Wave processes 2 edges per load instruction; 8 loads kept in flight
// (avg degree 16 -> the 8-pair body runs once). v/b1/W2 loads hoisted
// above the gather loop to overlap latency.
__global__ __launch_bounds__(256) void k_agg(
    const unsigned short* __restrict__ u, const unsigned short* __restrict__ v,
    const int* __restrict__ csr, const int* __restrict__ off, const int* __restrict__ deg,
    const float* __restrict__ b1,
    const float* __restrict__ W2l, const float* __restrict__ W2r,
    float* __restrict__ p, float* __restrict__ r) {
  int wid = (blockIdx.x * blockDim.x + threadIdx.x) >> 6;  // node
  int l = threadIdx.x & 63;
  if (wid >= NN) return;
  int cnt = deg[wid], st = off[wid];
  int half = l >> 5;
  int dpos = l & 31;
  const char* ubase = (const char*)u + (dpos << 3);

  // hoisted epilogue operands (overlap with gather latency)
  uint2 vw = *(const uint2*)((const char*)v + ((size_t)wid << 8) + (dpos << 3));
  float4 bb = *(const float4*)(b1 + 4 * dpos);
  const float* Wbase = half ? W2r : W2l;
  float4 wv[4];
#pragma unroll
  for (int o = 0; o < 4; ++o) wv[o] = *(const float4*)(Wbase + o * 128 + 4 * dpos);

  float a0 = 0.f, a1 = 0.f, a2 = 0.f, a3 = 0.f;

#define LOADW(W, S) uint2 W = *(const uint2*)(ubase + ((size_t)((unsigned)(S) << 8)))
#define ACCW(W) { a0 += bflo(W.x); a1 += bfhi(W.x); a2 += bflo(W.y); a3 += bfhi(W.y); }

  for (int base = 0; base < cnt; base += 64) {
    int nloc = min(64, cnt - base);
    int idx = 0;
    if (l < nloc) idx = csr[st + base + l];
    int npair = nloc >> 1;
    int e = 0;
    for (; e + 8 <= npair; e += 8) {
      int s0 = __shfl(idx, 2 * e + half, 64);
      int s1 = __shfl(idx, 2 * (e + 1) + half, 64);
      int s2 = __shfl(idx, 2 * (e + 2) + half, 64);
      int s3 = __shfl(idx, 2 * (e + 3) + half, 64);
      int s4 = __shfl(idx, 2 * (e + 4) + half, 64);
      int s5 = __shfl(idx, 2 * (e + 5) + half, 64);
      int s6 = __shfl(idx, 2 * (e + 6) + half, 64);
      int s7 = __shfl(idx, 2 * (e + 7) + half, 64);
      LOADW(w0, s0);
      LOADW(w1, s1);
      LOADW(w2, s2);
      LOADW(w3, s3);
      LOADW(w4, s4);
      LOADW(w5, s5);
      LOADW(w6, s6);
      LOADW(w7, s7);
      ACCW(w0); ACCW(w1); ACCW(w2); ACCW(w3);
      ACCW(w4); ACCW(w5); ACCW(w6); ACCW(w7);
    }
    for (; e + 4 <= npair; e += 4) {
      int s0 = __shfl(idx, 2 * e + half, 64);
      int s1 = __shfl(idx, 2 * (e + 1) + half, 64);
      int s2 = __shfl(idx, 2 * (e + 2) + half, 64);
      int s3 = __shfl(idx, 2 * (e + 3) + half, 64);
      LOADW(w0, s0);
      LOADW(w1, s1);
      LOADW(w2, s2);
      LOADW(w3, s3);
      ACCW(w0); ACCW(w1); ACCW(w2); ACCW(w3);
    }
    for (; e < npair; ++e) {
      int s = __shfl(idx, 2 * e + half, 64);
      LOADW(w, s);
      ACCW(w);
    }
    if (nloc & 1) {
      int s = __shfl(idx, nloc - 1, 64);
      if (half == 0) {
        LOADW(w, s);
        ACCW(w);
      }
    }
  }
#undef LOADW
#undef ACCW

  // merge the two edge-halves; afterwards both halves hold full sums
  a0 += __shfl_xor(a0, 32, 64);
  a1 += __shfl_xor(a1, 32, 64);
  a2 += __shfl_xor(a2, 32, 64);
  a3 += __shfl_xor(a3, 32, 64);

  float inv = 1.f / (float)max(cnt, 1);
  float h0 = fmaxf(fmaf(a0, inv, bflo(vw.x) + bb.x), 0.f);
  float h1 = fmaxf(fmaf(a1, inv, bfhi(vw.x) + bb.y), 0.f);
  float h2 = fmaxf(fmaf(a2, inv, bflo(vw.y) + bb.z), 0.f);
  float h3 = fmaxf(fmaf(a3, inv, bfhi(vw.y) + bb.w), 0.f);

  // half 0 -> p = h@W2l^T ; half 1 -> r = h@W2r^T  (4 outputs each)
  float* outp = half ? r : p;
#pragma unroll
  for (int o = 0; o < 4; ++o) {
    float s = h0 * wv[o].x + h1 * wv[o].y + h2 * wv[o].z + h3 * wv[o].w;
#pragma unroll
    for (int d = 16; d > 0; d >>= 1) s += __shfl_xor(s, d, 64);  // stays in half
    if (dpos == o) outp[(size_t)wid * 4 + o] = s;
  }
}

// ---------------- layer-2 aggregation (4-wide) + final linear ----------------
__global__ void k_final(const float* __restrict__ p, const float* __restrict__ r,
                        const int* __restrict__ csr, const int* __restrict__ off,
                        const int* __restrict__ deg,
                        const float* __restrict__ b2,
                        const float* __restrict__ Wlin, const float* __restrict__ blin,
                        float* __restrict__ out) {
  int i = blockIdx.x * blockDim.x + threadIdx.x;
  if (i >= NN) return;
  int cnt = deg[i], st = off[i];
  float a0 = 0.f, a1 = 0.f, a2 = 0.f, a3 = 0.f;
  for (int e = 0; e < cnt; ++e) {
    int s = csr[st + e];
    const float4 pv = *(const float4*)(p + (size_t)s * 4);
    a0 += pv.x; a1 += pv.y; a2 += pv.z; a3 += pv.w;
  }
  float inv = 1.f / (float)max(cnt, 1);
  float4 rv = *(const float4*)(r + (size_t)i * 4);
  float g0 = a0 * inv + b2[0] + rv.x;
  float g1 = a1 * inv + b2[1] + rv.y;
  float g2 = a2 * inv + b2[2] + rv.z;
  float g3 = a3 * inv + b2[3] + rv.w;
  out[(size_t)i * 2 + 0] = g0 * Wlin[0] + g1 * Wlin[1] + g2 * Wlin[2] + g3 * Wlin[3] + blin[0];
  out[(size_t)i * 2 + 1] = g0 * Wlin[4] + g1 * Wlin[5] + g2 * Wlin[6] + g3 * Wlin[7] + blin[1];
}

// ---------------- launch ----------------

extern "C" void kernel_launch(void* const* d_in, const int* in_sizes, int n_in,
                              void* d_out, int out_size, void* d_ws, size_t ws_size,
                              hipStream_t stream) {
  const float* x    = (const float*)d_in[0];
  const int*   ei   = (const int*)d_in[1];
  const int*   src  = ei;
  const int*   dst  = ei + NE;
  const float* W1l  = (const float*)d_in[2];
  const float* b1   = (const float*)d_in[3];
  const float* W1r  = (const float*)d_in[4];
  const float* W2l  = (const float*)d_in[5];
  const float* b2   = (const float*)d_in[6];
  const float* W2r  = (const float*)d_in[7];
  const float* Wlin = (const float*)d_in[8];
  const float* blin = (const float*)d_in[9];
  float* out = (float*)d_out;

  char* w = (char*)d_ws;
  size_t o = 0;
  auto alloc = [&](size_t bytes) {
    void* pp = (void*)(w + o);
    o = (o + bytes + 255) & ~(size_t)255;
    return pp;
  };
  int* hist  = (int*)alloc(NBUK * 4);
  int* bbase = (int*)alloc(NBUK * 4);
  int* gcur  = (int*)alloc(NBUK * 4);
  unsigned int*  staged = (unsigned int*)alloc((size_t)NE * 4);
  int* csr   = (int*)alloc((size_t)NE * 4);
  int* offs  = (int*)alloc(NN * 4);
  int* deg   = (int*)alloc(NN * 4);
  unsigned short* Wcat  = (unsigned short*)alloc(256 * 128 * 2);
  unsigned short* ubuf  = (unsigned short*)alloc((size_t)NN * 128 * 2);
  unsigned short* vbuf  = (unsigned short*)alloc((size_t)NN * 128 * 2);
  float* pbuf = (float*)alloc((size_t)NN * 4 * 4);
  float* rbuf = (float*)alloc((size_t)NN * 4 * 4);

  const size_t scatter_lds = (size_t)EB * 4 + (size_t)EB * 2 + (size_t)4 * NBUK * 4;

  hipLaunchKernelGGL(k_zerob, dim3((NBUK + 255) / 256), dim3(256), 0, stream, hist);
  hipLaunchKernelGGL(k_hist,  dim3((NE + 16383) / 16384), dim3(256), 0, stream, dst, hist);
  hipLaunchKernelGGL(k_scanb, dim3(1), dim3(256), 0, stream, hist, bbase, gcur);
  hipLaunchKernelGGL(k_scatter, dim3((NE + EB - 1) / EB), dim3(256), scatter_lds, stream,
                     src, dst, gcur, staged);
  hipLaunchKernelGGL(k_sort2, dim3(NBUK), dim3(256), 0, stream,
                     staged, bbase, hist, csr, offs, deg);
  hipLaunchKernelGGL(k_packw, dim3(128), dim3(256), 0, stream, W1l, W1r, Wcat);
  hipLaunchKernelGGL(k_gemm1, dim3((NN + 63) / 64), dim3(256), 0, stream, x, Wcat, ubuf, vbuf);
  hipLaunchKernelGGL(k_agg,   dim3((NN * 64 + 255) / 256), dim3(256), 0, stream,
                     ubuf, vbuf, csr, offs, deg, b1, W2l, W2r, pbuf, rbuf);
  hipLaunchKernelGGL(k_final, dim3((NN + 255) / 256), dim3(256), 0, stream,
                     pbuf, rbuf, csr, offs, deg, b2, Wlin, blin, out);
}

// Round 6
// 317.807 us; speedup vs baseline: 1.1424x; 1.0220x over previous
//
#include <hip/hip_runtime.h>

#define NN 100000
#define NE 1600000
#define NBUK 1563          // ceil(NN/64) buckets of 64 nodes
#define EB 8192            // edges per scatter block

typedef __attribute__((ext_vector_type(8))) short v8s;
typedef __attribute__((ext_vector_type(4))) float v4f;

__device__ __forceinline__ unsigned short f2bf(float f) {
  unsigned int u = __float_as_uint(f);
  unsigned int r = (u + 0x7FFFu + ((u >> 16) & 1u)) >> 16;
  return (unsigned short)r;
}
__device__ __forceinline__ float bflo(unsigned int w) { return __uint_as_float(w << 16); }
__device__ __forceinline__ float bfhi(unsigned int w) { return __uint_as_float(w & 0xFFFF0000u); }
__device__ __forceinline__ float bf2f(unsigned short w) {
  return __uint_as_float((unsigned int)w << 16);
}

// ---------------- bucket histogram ----------------

__global__ void k_zerob(int* __restrict__ hist) {
  int i = blockIdx.x * blockDim.x + threadIdx.x;
  if (i < NBUK) hist[i] = 0;
}

__global__ __launch_bounds__(256) void k_hist(const int* __restrict__ dst,
                                              int* __restrict__ hist) {
  __shared__ int lh[NBUK];
  int t = threadIdx.x;
  for (int i = t; i < NBUK; i += 256) lh[i] = 0;
  __syncthreads();
  int base = blockIdx.x * 16384;
  int lim = min(16384, NE - base);
  for (int j = t; j < lim; j += 256) atomicAdd(&lh[dst[base + j] >> 6], 1);
  __syncthreads();
  for (int i = t; i < NBUK; i += 256) {
    int c = lh[i];
    if (c) atomicAdd(&hist[i], c);
  }
}

// single-block chunked exclusive scan: hist -> bbase, gcur
__global__ __launch_bounds__(256) void k_scanb(const int* __restrict__ hist,
                                               int* __restrict__ bbase,
                                               int* __restrict__ gcur) {
  __shared__ int sc[256];
  __shared__ int carry;
  int t = threadIdx.x;
  if (t == 0) carry = 0;
  __syncthreads();
  for (int c = 0; c < (NBUK + 255) / 256; ++c) {
    int i = c * 256 + t;
    int vv = (i < NBUK) ? hist[i] : 0;
    sc[t] = vv;
    __syncthreads();
    for (int o = 1; o < 256; o <<= 1) {
      int uu = (t >= o) ? sc[t - o] : 0;
      __syncthreads();
      sc[t] += uu;
      __syncthreads();
    }
    int excl = carry + sc[t] - vv;
    if (i < NBUK) { bbase[i] = excl; gcur[i] = excl; }
    __syncthreads();
    if (t == 0) carry += sc[255];
    __syncthreads();
  }
}

// ---------------- LDS-staged bucket scatter (linear global writes) ---------
// staged[k] = (src<<6) | dstLocal, bucket-sorted.
extern __shared__ char smem_dyn[];
__global__ __launch_bounds__(256) void k_scatter(const int* __restrict__ src,
                                                 const int* __restrict__ dst,
                                                 int* __restrict__ gcur,
                                                 unsigned int* __restrict__ staged) {
  unsigned int* stageP = (unsigned int*)smem_dyn;              // EB
  unsigned short* stageB = (unsigned short*)(stageP + EB);     // EB
  int* lhist  = (int*)(stageB + EB);                           // NBUK
  int* lbase  = lhist + NBUK;
  int* lcur   = lbase + NBUK;
  int* gclaim = lcur + NBUK;
  __shared__ int sc[256];
  __shared__ int carry;
  int t = threadIdx.x;
  int e0 = blockIdx.x * EB;
  int ecnt = min(EB, NE - e0);
  for (int i = t; i < NBUK; i += 256) lhist[i] = 0;
  if (t == 0) carry = 0;
  __syncthreads();
  for (int j = t; j < ecnt; j += 256) atomicAdd(&lhist[dst[e0 + j] >> 6], 1);
  __syncthreads();
  for (int c = 0; c < (NBUK + 255) / 256; ++c) {
    int i = c * 256 + t;
    int vv = (i < NBUK) ? lhist[i] : 0;
    sc[t] = vv;
    __syncthreads();
    for (int o = 1; o < 256; o <<= 1) {
      int uu = (t >= o) ? sc[t - o] : 0;
      __syncthreads();
      sc[t] += uu;
      __syncthreads();
    }
    int excl = carry + sc[t] - vv;
    if (i < NBUK) { lbase[i] = excl; lcur[i] = excl; }
    __syncthreads();
    if (t == 0) carry += sc[255];
    __syncthreads();
  }
  for (int b = t; b < NBUK; b += 256) {
    int c = lhist[b];
    gclaim[b] = c ? atomicAdd(&gcur[b], c) : 0;
  }
  __syncthreads();
  for (int j = t; j < ecnt; j += 256) {
    int s = src[e0 + j], d = dst[e0 + j];
    int b = d >> 6;
    int lp = atomicAdd(&lcur[b], 1);
    stageP[lp] = ((unsigned int)s << 6) | (unsigned int)(d & 63);
    stageB[lp] = (unsigned short)b;
  }
  __syncthreads();
  for (int i = t; i < ecnt; i += 256) {
    int b = stageB[i];
    staged[gclaim[b] + (i - lbase[b])] = stageP[i];
  }
}

// ---------------- per-bucket radix pass 2: staged -> CSR + off + deg -------
__global__ __launch_bounds__(256) void k_sort2(const unsigned int* __restrict__ staged,
                                               const int* __restrict__ bbase,
                                               const int* __restrict__ hist,
                                               int* __restrict__ csr,
                                               int* __restrict__ off,
                                               int* __restrict__ deg) {
  __shared__ int h64[64], c64[64];
  int bkt = blockIdx.x, t = threadIdx.x;
  if (t < 64) h64[t] = 0;
  __syncthreads();
  int st = bbase[bkt], cnt = hist[bkt];
  for (int j = t; j < cnt; j += 256) atomicAdd(&h64[staged[st + j] & 63], 1);
  __syncthreads();
  if (t < 64) {
    int v = h64[t];
    int inc = v;
    for (int o = 1; o < 64; o <<= 1) {
      int uu = __shfl_up(inc, o, 64);
      if (t >= o) inc += uu;
    }
    int excl = inc - v;
    c64[t] = excl;
    int node = bkt * 64 + t;
    if (node < NN) { off[node] = st + excl; deg[node] = v; }
  }
  __syncthreads();
  for (int j = t; j < cnt; j += 256) {
    unsigned pk = staged[st + j];
    int lp = atomicAdd(&c64[pk & 63], 1);
    csr[st + lp] = (int)(pk >> 6);
  }
}

// ---------------- weight pack ----------------

__global__ void k_packw(const float* __restrict__ W1l, const float* __restrict__ W1r,
                        unsigned short* __restrict__ Wcat) {
  int i = blockIdx.x * blockDim.x + threadIdx.x;  // 0..32767
  float f = (i < 16384) ? W1l[i] : W1r[i - 16384];
  Wcat[i] = f2bf(f);
}

// ---------------- MFMA GEMM: u = x@W1l^T, v = x@W1r^T (bf16 out) ----------
__global__ __launch_bounds__(256) void k_gemm1(
    const float* __restrict__ x, const unsigned short* __restrict__ Wcat,
    unsigned short* __restrict__ u, unsigned short* __restrict__ v) {
  int wave = threadIdx.x >> 6, l = threadIdx.x & 63;
  int m0 = blockIdx.x * 64 + wave * 16;
  if (m0 >= NN) return;
  int lr = l & 15, kq = l >> 4;
  int rowc = min(m0 + lr, NN - 1);

  v8s a[4];
#pragma unroll
  for (int ks = 0; ks < 4; ++ks) {
    const float* xp = x + (size_t)rowc * 128 + ks * 32 + kq * 8;
    float4 f0 = *(const float4*)xp;
    float4 f1 = *(const float4*)(xp + 4);
    v8s tv;
    tv[0] = (short)f2bf(f0.x); tv[1] = (short)f2bf(f0.y);
    tv[2] = (short)f2bf(f0.z); tv[3] = (short)f2bf(f0.w);
    tv[4] = (short)f2bf(f1.x); tv[5] = (short)f2bf(f1.y);
    tv[6] = (short)f2bf(f1.z); tv[7] = (short)f2bf(f1.w);
    a[ks] = tv;
  }

  v4f acc[16];
#pragma unroll
  for (int nt = 0; nt < 16; ++nt) acc[nt] = (v4f){0.f, 0.f, 0.f, 0.f};

#pragma unroll
  for (int nt = 0; nt < 16; ++nt) {
    const unsigned short* wrow = Wcat + (size_t)(nt * 16 + lr) * 128;
#pragma unroll
    for (int ks = 0; ks < 4; ++ks) {
      v8s b = *(const v8s*)(wrow + ks * 32 + kq * 8);
      acc[nt] = __builtin_amdgcn_mfma_f32_16x16x32_bf16(a[ks], b, acc[nt], 0, 0, 0);
    }
  }

#pragma unroll
  for (int nt = 0; nt < 16; ++nt) {
#pragma unroll
    for (int rr = 0; rr < 4; ++rr) {
      int mrow = m0 + kq * 4 + rr;
      if (mrow < NN) {
        unsigned short bv = f2bf(acc[nt][rr]);
        int col = nt * 16 + lr;
        if (nt < 8) u[(size_t)mrow * 128 + col] = bv;
        else        v[(size_t)mrow * 128 + (col - 128)] = bv;
      }
    }
  }
}

// ---------------- fused: mean-agg(u) + v + b1 -> relu -> h1; p=h1@W2l^T,
//                  r=h1@W2r^T.
// One wave per node; half = l>>5 picks edge of a pair, dpos = l&31 covers
// dims 4*dpos..+3. Epilogue uses a multi-value butterfly: 5 shfl for all
// 4 outputs per half (vs 20 in the per-output tree).
__global__ __launch_bounds__(256) void k_agg(
    const unsigned short* __restrict__ u, const unsigned short* __restrict__ v,
    const int* __restrict__ csr, const int* __restrict__ off, const int* __restrict__ deg,
    const float* __restrict__ b1,
    const float* __restrict__ W2l, const float* __restrict__ W2r,
    float* __restrict__ p, float* __restrict__ r) {
  int wid = (blockIdx.x * blockDim.x + threadIdx.x) >> 6;  // node
  int l = threadIdx.x & 63;
  if (wid >= NN) return;
  int cnt = deg[wid], st = off[wid];
  int half = l >> 5;
  int dpos = l & 31;
  const char* ubase = (const char*)u + (dpos << 3);

  // hoisted epilogue operands (overlap with gather latency)
  uint2 vw = *(const uint2*)((const char*)v + ((size_t)wid << 8) + (dpos << 3));
  float4 bb = *(const float4*)(b1 + 4 * dpos);
  const float* Wbase = half ? W2r : W2l;
  float4 wv[4];
#pragma unroll
  for (int o = 0; o < 4; ++o) wv[o] = *(const float4*)(Wbase + o * 128 + 4 * dpos);

  float a0 = 0.f, a1 = 0.f, a2 = 0.f, a3 = 0.f;

#define LOADW(W, S) uint2 W = *(const uint2*)(ubase + ((size_t)((unsigned)(S) << 8)))
#define ACCW(W) { a0 += bflo(W.x); a1 += bfhi(W.x); a2 += bflo(W.y); a3 += bfhi(W.y); }

  for (int base = 0; base < cnt; base += 64) {
    int nloc = min(64, cnt - base);
    int idx = 0;
    if (l < nloc) idx = csr[st + base + l];
    int npair = nloc >> 1;
    int e = 0;
    for (; e + 8 <= npair; e += 8) {
      int s0 = __shfl(idx, 2 * e + half, 64);
      int s1 = __shfl(idx, 2 * (e + 1) + half, 64);
      int s2 = __shfl(idx, 2 * (e + 2) + half, 64);
      int s3 = __shfl(idx, 2 * (e + 3) + half, 64);
      int s4 = __shfl(idx, 2 * (e + 4) + half, 64);
      int s5 = __shfl(idx, 2 * (e + 5) + half, 64);
      int s6 = __shfl(idx, 2 * (e + 6) + half, 64);
      int s7 = __shfl(idx, 2 * (e + 7) + half, 64);
      LOADW(w0, s0);
      LOADW(w1, s1);
      LOADW(w2, s2);
      LOADW(w3, s3);
      LOADW(w4, s4);
      LOADW(w5, s5);
      LOADW(w6, s6);
      LOADW(w7, s7);
      ACCW(w0); ACCW(w1); ACCW(w2); ACCW(w3);
      ACCW(w4); ACCW(w5); ACCW(w6); ACCW(w7);
    }
    for (; e + 4 <= npair; e += 4) {
      int s0 = __shfl(idx, 2 * e + half, 64);
      int s1 = __shfl(idx, 2 * (e + 1) + half, 64);
      int s2 = __shfl(idx, 2 * (e + 2) + half, 64);
      int s3 = __shfl(idx, 2 * (e + 3) + half, 64);
      LOADW(w0, s0);
      LOADW(w1, s1);
      LOADW(w2, s2);
      LOADW(w3, s3);
      ACCW(w0); ACCW(w1); ACCW(w2); ACCW(w3);
    }
    for (; e < npair; ++e) {
      int s = __shfl(idx, 2 * e + half, 64);
      LOADW(w, s);
      ACCW(w);
    }
    if (nloc & 1) {
      int s = __shfl(idx, nloc - 1, 64);
      if (half == 0) {
        LOADW(w, s);
        ACCW(w);
      }
    }
  }
#undef LOADW
#undef ACCW

  // merge the two edge-halves; afterwards both halves hold full sums
  a0 += __shfl_xor(a0, 32, 64);
  a1 += __shfl_xor(a1, 32, 64);
  a2 += __shfl_xor(a2, 32, 64);
  a3 += __shfl_xor(a3, 32, 64);

  float inv = 1.f / (float)max(cnt, 1);
  float h0 = fmaxf(fmaf(a0, inv, bflo(vw.x) + bb.x), 0.f);
  float h1 = fmaxf(fmaf(a1, inv, bfhi(vw.x) + bb.y), 0.f);
  float h2 = fmaxf(fmaf(a2, inv, bflo(vw.y) + bb.z), 0.f);
  float h3 = fmaxf(fmaf(a3, inv, bfhi(vw.y) + bb.w), 0.f);

  // half 0 -> p = h@W2l^T ; half 1 -> r = h@W2r^T  (4 outputs each)
  float t0 = h0 * wv[0].x + h1 * wv[0].y + h2 * wv[0].z + h3 * wv[0].w;
  float t1 = h0 * wv[1].x + h1 * wv[1].y + h2 * wv[1].z + h3 * wv[1].w;
  float t2 = h0 * wv[2].x + h1 * wv[2].y + h2 * wv[2].z + h3 * wv[2].w;
  float t3 = h0 * wv[3].x + h1 * wv[3].y + h2 * wv[3].z + h3 * wv[3].w;
  // multi-value butterfly: after stage 2, lane (l&3)==o holds output o
  float v01 = (l & 1) ? t1 : t0;
  float w01 = __shfl_xor((l & 1) ? t0 : t1, 1, 64);
  float r01 = v01 + w01;
  float v23 = (l & 1) ? t3 : t2;
  float w23 = __shfl_xor((l & 1) ? t2 : t3, 1, 64);
  float r23 = v23 + w23;
  float vq = (l & 2) ? r23 : r01;
  float wq = __shfl_xor((l & 2) ? r01 : r23, 2, 64);
  float rr = vq + wq;
  rr += __shfl_xor(rr, 4, 64);
  rr += __shfl_xor(rr, 8, 64);
  rr += __shfl_xor(rr, 16, 64);
  float* outp = half ? r : p;
  if (dpos < 4) outp[(size_t)wid * 4 + dpos] = rr;
}

// ---------------- layer-2 aggregation + final linear --------------------
// 8 lanes per node: lanes gather 8 edges in parallel (csr reads 32B
// contiguous per group), multi-value butterfly reduces all 4 dims, then a
// 2-shfl projection produces both outputs. 3125 blocks (vs 391 before).
__global__ __launch_bounds__(256) void k_final(
    const float* __restrict__ p, const float* __restrict__ r,
    const int* __restrict__ csr, const int* __restrict__ off,
    const int* __restrict__ deg,
    const float* __restrict__ b2,
    const float* __restrict__ Wlin, const float* __restrict__ blin,
    float* __restrict__ out) {
  int gid = blockIdx.x * blockDim.x + threadIdx.x;
  int node = gid >> 3;
  int sl = gid & 7;
  if (node >= NN) return;
  int cnt = deg[node], st = off[node];
  int l = threadIdx.x & 63;

  float a0 = 0.f, a1 = 0.f, a2 = 0.f, a3 = 0.f;
  for (int e = sl; e < cnt; e += 8) {
    int s = csr[st + e];
    const float4 pv = *(const float4*)(p + (size_t)s * 4);
    a0 += pv.x; a1 += pv.y; a2 += pv.z; a3 += pv.w;
  }
  // multi-value reduce within the 8-lane group
  float v01 = (l & 1) ? a1 : a0;
  float w01 = __shfl_xor((l & 1) ? a0 : a1, 1, 64);
  float r01 = v01 + w01;
  float v23 = (l & 1) ? a3 : a2;
  float w23 = __shfl_xor((l & 1) ? a2 : a3, 1, 64);
  float r23 = v23 + w23;
  float vq = (l & 2) ? r23 : r01;
  float wq = __shfl_xor((l & 2) ? r01 : r23, 2, 64);
  float rr = vq + wq;
  rr += __shfl_xor(rr, 4, 64);
  // lane (sl&3)==o holds agg_o over all 8 lanes
  int o = sl & 3;
  float inv = 1.f / (float)max(cnt, 1);
  float g = rr * inv + b2[o] + r[(size_t)node * 4 + o];
  // project onto Wlin rows: out0 = sum g_o*Wlin[o], out1 = sum g_o*Wlin[4+o]
  float t0 = g * Wlin[o];
  float t1 = g * Wlin[4 + o];
  float vv = (l & 1) ? t1 : t0;
  float ww = __shfl_xor((l & 1) ? t0 : t1, 1, 64);
  float q = vv + ww;
  q += __shfl_xor(q, 2, 64);
  if (sl < 2) out[(size_t)node * 2 + sl] = q + blin[sl];
}

// ---------------- launch ----------------

extern "C" void kernel_launch(void* const* d_in, const int* in_sizes, int n_in,
                              void* d_out, int out_size, void* d_ws, size_t ws_size,
                              hipStream_t stream) {
  const float* x    = (const float*)d_in[0];
  const int*   ei   = (const int*)d_in[1];
  const int*   src  = ei;
  const int*   dst  = ei + NE;
  const float* W1l  = (const float*)d_in[2];
  const float* b1   = (const float*)d_in[3];
  const float* W1r  = (const float*)d_in[4];
  const float* W2l  = (const float*)d_in[5];
  const float* b2   = (const float*)d_in[6];
  const float* W2r  = (const float*)d_in[7];
  const float* Wlin = (const float*)d_in[8];
  const float* blin = (const float*)d_in[9];
  float* out = (float*)d_out;

  char* w = (char*)d_ws;
  size_t o = 0;
  auto alloc = [&](size_t bytes) {
    void* pp = (void*)(w + o);
    o = (o + bytes + 255) & ~(size_t)255;
    return pp;
  };
  int* hist  = (int*)alloc(NBUK * 4);
  int* bbase = (int*)alloc(NBUK * 4);
  int* gcur  = (int*)alloc(NBUK * 4);
  unsigned int*  staged = (unsigned int*)alloc((size_t)NE * 4);
  int* csr   = (int*)alloc((size_t)NE * 4);
  int* offs  = (int*)alloc(NN * 4);
  int* deg   = (int*)alloc(NN * 4);
  unsigned short* Wcat  = (unsigned short*)alloc(256 * 128 * 2);
  unsigned short* ubuf  = (unsigned short*)alloc((size_t)NN * 128 * 2);
  unsigned short* vbuf  = (unsigned short*)alloc((size_t)NN * 128 * 2);
  float* pbuf = (float*)alloc((size_t)NN * 4 * 4);
  float* rbuf = (float*)alloc((size_t)NN * 4 * 4);

  const size_t scatter_lds = (size_t)EB * 4 + (size_t)EB * 2 + (size_t)4 * NBUK * 4;

  hipLaunchKernelGGL(k_zerob, dim3((NBUK + 255) / 256), dim3(256), 0, stream, hist);
  hipLaunchKernelGGL(k_hist,  dim3((NE + 16383) / 16384), dim3(256), 0, stream, dst, hist);
  hipLaunchKernelGGL(k_scanb, dim3(1), dim3(256), 0, stream, hist, bbase, gcur);
  hipLaunchKernelGGL(k_scatter, dim3((NE + EB - 1) / EB), dim3(256), scatter_lds, stream,
                     src, dst, gcur, staged);
  hipLaunchKernelGGL(k_sort2, dim3(NBUK), dim3(256), 0, stream,
                     staged, bbase, hist, csr, offs, deg);
  hipLaunchKernelGGL(k_packw, dim3(128), dim3(256), 0, stream, W1l, W1r, Wcat);
  hipLaunchKernelGGL(k_gemm1, dim3((NN + 63) / 64), dim3(256), 0, stream, x, Wcat, ubuf, vbuf);
  hipLaunchKernelGGL(k_agg,   dim3((NN * 64 + 255) / 256), dim3(256), 0, stream,
                     ubuf, vbuf, csr, offs, deg, b1, W2l, W2r, pbuf, rbuf);
  hipLaunchKernelGGL(k_final, dim3((NN * 8 + 255) / 256), dim3(256), 0, stream,
                     pbuf, rbuf, csr, offs, deg, b2, Wlin, blin, out);
}

// Round 7
// 280.959 us; speedup vs baseline: 1.2922x; 1.1312x over previous
//
#include <hip/hip_runtime.h>

#define NN 100000
#define NE 1600000
#define NBUK 1563          // ceil(NN/64) buckets of 64 nodes
#define EB 8192            // edges per scatter block

typedef __attribute__((ext_vector_type(8))) short v8s;
typedef __attribute__((ext_vector_type(4))) float v4f;

__device__ __forceinline__ unsigned short f2bf(float f) {
  unsigned int u = __float_as_uint(f);
  unsigned int r = (u + 0x7FFFu + ((u >> 16) & 1u)) >> 16;
  return (unsigned short)r;
}
__device__ __forceinline__ float bflo(unsigned int w) { return __uint_as_float(w << 16); }
__device__ __forceinline__ float bfhi(unsigned int w) { return __uint_as_float(w & 0xFFFF0000u); }
__device__ __forceinline__ float bf2f(unsigned short w) {
  return __uint_as_float((unsigned int)w << 16);
}

// ---------------- bucket histogram ----------------

__global__ void k_zerob(int* __restrict__ hist) {
  int i = blockIdx.x * blockDim.x + threadIdx.x;
  if (i < NBUK) hist[i] = 0;
}

__global__ __launch_bounds__(256) void k_hist(const int* __restrict__ dst,
                                              int* __restrict__ hist) {
  __shared__ int lh[NBUK];
  int t = threadIdx.x;
  for (int i = t; i < NBUK; i += 256) lh[i] = 0;
  __syncthreads();
  int base = blockIdx.x * 16384;
  int lim = min(16384, NE - base);
  for (int j = t; j < lim; j += 256) atomicAdd(&lh[dst[base + j] >> 6], 1);
  __syncthreads();
  for (int i = t; i < NBUK; i += 256) {
    int c = lh[i];
    if (c) atomicAdd(&hist[i], c);
  }
}

// single-block chunked exclusive scan: hist -> bbase, gcur
__global__ __launch_bounds__(256) void k_scanb(const int* __restrict__ hist,
                                               int* __restrict__ bbase,
                                               int* __restrict__ gcur) {
  __shared__ int sc[256];
  __shared__ int carry;
  int t = threadIdx.x;
  if (t == 0) carry = 0;
  __syncthreads();
  for (int c = 0; c < (NBUK + 255) / 256; ++c) {
    int i = c * 256 + t;
    int vv = (i < NBUK) ? hist[i] : 0;
    sc[t] = vv;
    __syncthreads();
    for (int o = 1; o < 256; o <<= 1) {
      int uu = (t >= o) ? sc[t - o] : 0;
      __syncthreads();
      sc[t] += uu;
      __syncthreads();
    }
    int excl = carry + sc[t] - vv;
    if (i < NBUK) { bbase[i] = excl; gcur[i] = excl; }
    __syncthreads();
    if (t == 0) carry += sc[255];
    __syncthreads();
  }
}

// ---------------- LDS-staged bucket scatter (linear global writes) ---------
// staged[k] = (src<<6) | dstLocal, bucket-sorted.
extern __shared__ char smem_dyn[];
__global__ __launch_bounds__(256) void k_scatter(const int* __restrict__ src,
                                                 const int* __restrict__ dst,
                                                 int* __restrict__ gcur,
                                                 unsigned int* __restrict__ staged) {
  unsigned int* stageP = (unsigned int*)smem_dyn;              // EB
  unsigned short* stageB = (unsigned short*)(stageP + EB);     // EB
  int* lhist  = (int*)(stageB + EB);                           // NBUK
  int* lbase  = lhist + NBUK;
  int* lcur   = lbase + NBUK;
  int* gclaim = lcur + NBUK;
  __shared__ int sc[256];
  __shared__ int carry;
  int t = threadIdx.x;
  int e0 = blockIdx.x * EB;
  int ecnt = min(EB, NE - e0);
  for (int i = t; i < NBUK; i += 256) lhist[i] = 0;
  if (t == 0) carry = 0;
  __syncthreads();
  for (int j = t; j < ecnt; j += 256) atomicAdd(&lhist[dst[e0 + j] >> 6], 1);
  __syncthreads();
  for (int c = 0; c < (NBUK + 255) / 256; ++c) {
    int i = c * 256 + t;
    int vv = (i < NBUK) ? lhist[i] : 0;
    sc[t] = vv;
    __syncthreads();
    for (int o = 1; o < 256; o <<= 1) {
      int uu = (t >= o) ? sc[t - o] : 0;
      __syncthreads();
      sc[t] += uu;
      __syncthreads();
    }
    int excl = carry + sc[t] - vv;
    if (i < NBUK) { lbase[i] = excl; lcur[i] = excl; }
    __syncthreads();
    if (t == 0) carry += sc[255];
    __syncthreads();
  }
  for (int b = t; b < NBUK; b += 256) {
    int c = lhist[b];
    gclaim[b] = c ? atomicAdd(&gcur[b], c) : 0;
  }
  __syncthreads();
  for (int j = t; j < ecnt; j += 256) {
    int s = src[e0 + j], d = dst[e0 + j];
    int b = d >> 6;
    int lp = atomicAdd(&lcur[b], 1);
    stageP[lp] = ((unsigned int)s << 6) | (unsigned int)(d & 63);
    stageB[lp] = (unsigned short)b;
  }
  __syncthreads();
  for (int i = t; i < ecnt; i += 256) {
    int b = stageB[i];
    staged[gclaim[b] + (i - lbase[b])] = stageP[i];
  }
}

// ---------------- per-bucket radix pass 2: staged -> CSR + off + deg -------
__global__ __launch_bounds__(256) void k_sort2(const unsigned int* __restrict__ staged,
                                               const int* __restrict__ bbase,
                                               const int* __restrict__ hist,
                                               int* __restrict__ csr,
                                               int* __restrict__ off,
                                               int* __restrict__ deg) {
  __shared__ int h64[64], c64[64];
  int bkt = blockIdx.x, t = threadIdx.x;
  if (t < 64) h64[t] = 0;
  __syncthreads();
  int st = bbase[bkt], cnt = hist[bkt];
  for (int j = t; j < cnt; j += 256) atomicAdd(&h64[staged[st + j] & 63], 1);
  __syncthreads();
  if (t < 64) {
    int v = h64[t];
    int inc = v;
    for (int o = 1; o < 64; o <<= 1) {
      int uu = __shfl_up(inc, o, 64);
      if (t >= o) inc += uu;
    }
    int excl = inc - v;
    c64[t] = excl;
    int node = bkt * 64 + t;
    if (node < NN) { off[node] = st + excl; deg[node] = v; }
  }
  __syncthreads();
  for (int j = t; j < cnt; j += 256) {
    unsigned pk = staged[st + j];
    int lp = atomicAdd(&c64[pk & 63], 1);
    csr[st + lp] = (int)(pk >> 6);
  }
}

// ---------------- weight pack ----------------

__global__ void k_packw(const float* __restrict__ W1l, const float* __restrict__ W1r,
                        unsigned short* __restrict__ Wcat) {
  int i = blockIdx.x * blockDim.x + threadIdx.x;  // 0..32767
  float f = (i < 16384) ? W1l[i] : W1r[i - 16384];
  Wcat[i] = f2bf(f);
}

// ---------------- MFMA GEMM: u = x@W1l^T, v = x@W1r^T (bf16 out) ----------
// v2: W staged in LDS (pitch 272B -> 4-bank row skew, <=2-way conflict);
// operands SWAPPED (A=W, B=x) so each lane owns 4 consecutive output cols
// of one x-row -> 8B uint2 stores (16/lane) instead of 64 2B stores.
// Dynamic LDS: 256 rows * 272B = 69632 B -> 2 blocks/CU.
__global__ __launch_bounds__(256) void k_gemm1(
    const float* __restrict__ x, const unsigned short* __restrict__ Wcat,
    unsigned short* __restrict__ u, unsigned short* __restrict__ v) {
  char* wlds = smem_dyn;
  int t = threadIdx.x;
  // stage Wcat (256x128 bf16) -> LDS, 16 rows per round, 16B per thread
  {
    int rsub = t >> 4, chunk = t & 15;
#pragma unroll
    for (int rd = 0; rd < 16; ++rd) {
      int row = rd * 16 + rsub;
      uint4 w4 = *(const uint4*)(Wcat + (size_t)row * 128 + chunk * 8);
      *(uint4*)(wlds + row * 272 + chunk * 16) = w4;
    }
  }

  int wave = t >> 6, l = t & 63;
  int m0 = blockIdx.x * 64 + wave * 16;
  int lr = l & 15, kq = l >> 4;
  int rowc = min(m0 + lr, NN - 1);

  // x fragments (B operand after swap: col = lr = x-row, k = kq*8.. + ks*32)
  v8s a[4];
#pragma unroll
  for (int ks = 0; ks < 4; ++ks) {
    const float* xp = x + (size_t)rowc * 128 + ks * 32 + kq * 8;
    float4 f0 = *(const float4*)xp;
    float4 f1 = *(const float4*)(xp + 4);
    v8s tv;
    tv[0] = (short)f2bf(f0.x); tv[1] = (short)f2bf(f0.y);
    tv[2] = (short)f2bf(f0.z); tv[3] = (short)f2bf(f0.w);
    tv[4] = (short)f2bf(f1.x); tv[5] = (short)f2bf(f1.y);
    tv[6] = (short)f2bf(f1.z); tv[7] = (short)f2bf(f1.w);
    a[ks] = tv;
  }

  __syncthreads();   // LDS staging complete

  v4f acc[16];
#pragma unroll
  for (int nt = 0; nt < 16; ++nt) acc[nt] = (v4f){0.f, 0.f, 0.f, 0.f};

#pragma unroll
  for (int nt = 0; nt < 16; ++nt) {
    const char* wrow = wlds + (nt * 16 + lr) * 272;
#pragma unroll
    for (int ks = 0; ks < 4; ++ks) {
      v8s b = *(const v8s*)(wrow + ks * 64 + kq * 16);
      // swapped: A = W fragment, B = x fragment
      acc[nt] = __builtin_amdgcn_mfma_f32_16x16x32_bf16(b, a[ks], acc[nt], 0, 0, 0);
    }
  }

  // C[wrow][xrow]: col=lane&15 = x-row (lr), row=(l>>4)*4+rr = out col.
  // Lane writes cols nt*16 + kq*4 .. +3 of row m0+lr -> one 8B store per nt.
  if (m0 + lr < NN) {
    size_t rowb = (size_t)(m0 + lr) * 128;
#pragma unroll
    for (int nt = 0; nt < 16; ++nt) {
      unsigned lo = (unsigned)f2bf(acc[nt][0]) | ((unsigned)f2bf(acc[nt][1]) << 16);
      unsigned hi = (unsigned)f2bf(acc[nt][2]) | ((unsigned)f2bf(acc[nt][3]) << 16);
      int col = (nt & 7) * 16 + kq * 4;
      if (nt < 8) *(uint2*)(u + rowb + col) = make_uint2(lo, hi);
      else        *(uint2*)(v + rowb + col) = make_uint2(lo, hi);
    }
  }
}

// ---------------- fused: mean-agg(u) + v + b1 -> relu -> h1; p=h1@W2l^T,
//                  r=h1@W2r^T.
// One wave per node; half = l>>5 picks edge of a pair, dpos = l&31 covers
// dims 4*dpos..+3. Epilogue uses a multi-value butterfly: 5 shfl for all
// 4 outputs per half (vs 20 in the per-output tree).
__global__ __launch_bounds__(256) void k_agg(
    const unsigned short* __restrict__ u, const unsigned short* __restrict__ v,
    const int* __restrict__ csr, const int* __restrict__ off, const int* __restrict__ deg,
    const float* __restrict__ b1,
    const float* __restrict__ W2l, const float* __restrict__ W2r,
    float* __restrict__ p, float* __restrict__ r) {
  int wid = (blockIdx.x * blockDim.x + threadIdx.x) >> 6;  // node
  int l = threadIdx.x & 63;
  if (wid >= NN) return;
  int cnt = deg[wid], st = off[wid];
  int half = l >> 5;
  int dpos = l & 31;
  const char* ubase = (const char*)u + (dpos << 3);

  // hoisted epilogue operands (overlap with gather latency)
  uint2 vw = *(const uint2*)((const char*)v + ((size_t)wid << 8) + (dpos << 3));
  float4 bb = *(const float4*)(b1 + 4 * dpos);
  const float* Wbase = half ? W2r : W2l;
  float4 wv[4];
#pragma unroll
  for (int o = 0; o < 4; ++o) wv[o] = *(const float4*)(Wbase + o * 128 + 4 * dpos);

  float a0 = 0.f, a1 = 0.f, a2 = 0.f, a3 = 0.f;

#define LOADW(W, S) uint2 W = *(const uint2*)(ubase + ((size_t)((unsigned)(S) << 8)))
#define ACCW(W) { a0 += bflo(W.x); a1 += bfhi(W.x); a2 += bflo(W.y); a3 += bfhi(W.y); }

  for (int base = 0; base < cnt; base += 64) {
    int nloc = min(64, cnt - base);
    int idx = 0;
    if (l < nloc) idx = csr[st + base + l];
    int npair = nloc >> 1;
    int e = 0;
    for (; e + 8 <= npair; e += 8) {
      int s0 = __shfl(idx, 2 * e + half, 64);
      int s1 = __shfl(idx, 2 * (e + 1) + half, 64);
      int s2 = __shfl(idx, 2 * (e + 2) + half, 64);
      int s3 = __shfl(idx, 2 * (e + 3) + half, 64);
      int s4 = __shfl(idx, 2 * (e + 4) + half, 64);
      int s5 = __shfl(idx, 2 * (e + 5) + half, 64);
      int s6 = __shfl(idx, 2 * (e + 6) + half, 64);
      int s7 = __shfl(idx, 2 * (e + 7) + half, 64);
      LOADW(w0, s0);
      LOADW(w1, s1);
      LOADW(w2, s2);
      LOADW(w3, s3);
      LOADW(w4, s4);
      LOADW(w5, s5);
      LOADW(w6, s6);
      LOADW(w7, s7);
      ACCW(w0); ACCW(w1); ACCW(w2); ACCW(w3);
      ACCW(w4); ACCW(w5); ACCW(w6); ACCW(w7);
    }
    for (; e + 4 <= npair; e += 4) {
      int s0 = __shfl(idx, 2 * e + half, 64);
      int s1 = __shfl(idx, 2 * (e + 1) + half, 64);
      int s2 = __shfl(idx, 2 * (e + 2) + half, 64);
      int s3 = __shfl(idx, 2 * (e + 3) + half, 64);
      LOADW(w0, s0);
      LOADW(w1, s1);
      LOADW(w2, s2);
      LOADW(w3, s3);
      ACCW(w0); ACCW(w1); ACCW(w2); ACCW(w3);
    }
    for (; e < npair; ++e) {
      int s = __shfl(idx, 2 * e + half, 64);
      LOADW(w, s);
      ACCW(w);
    }
    if (nloc & 1) {
      int s = __shfl(idx, nloc - 1, 64);
      if (half == 0) {
        LOADW(w, s);
        ACCW(w);
      }
    }
  }
#undef LOADW
#undef ACCW

  // merge the two edge-halves; afterwards both halves hold full sums
  a0 += __shfl_xor(a0, 32, 64);
  a1 += __shfl_xor(a1, 32, 64);
  a2 += __shfl_xor(a2, 32, 64);
  a3 += __shfl_xor(a3, 32, 64);

  float inv = 1.f / (float)max(cnt, 1);
  float h0 = fmaxf(fmaf(a0, inv, bflo(vw.x) + bb.x), 0.f);
  float h1 = fmaxf(fmaf(a1, inv, bfhi(vw.x) + bb.y), 0.f);
  float h2 = fmaxf(fmaf(a2, inv, bflo(vw.y) + bb.z), 0.f);
  float h3 = fmaxf(fmaf(a3, inv, bfhi(vw.y) + bb.w), 0.f);

  // half 0 -> p = h@W2l^T ; half 1 -> r = h@W2r^T  (4 outputs each)
  float t0 = h0 * wv[0].x + h1 * wv[0].y + h2 * wv[0].z + h3 * wv[0].w;
  float t1 = h0 * wv[1].x + h1 * wv[1].y + h2 * wv[1].z + h3 * wv[1].w;
  float t2 = h0 * wv[2].x + h1 * wv[2].y + h2 * wv[2].z + h3 * wv[2].w;
  float t3 = h0 * wv[3].x + h1 * wv[3].y + h2 * wv[3].z + h3 * wv[3].w;
  // multi-value butterfly: after stage 2, lane (l&3)==o holds output o
  float v01 = (l & 1) ? t1 : t0;
  float w01 = __shfl_xor((l & 1) ? t0 : t1, 1, 64);
  float r01 = v01 + w01;
  float v23 = (l & 1) ? t3 : t2;
  float w23 = __shfl_xor((l & 1) ? t2 : t3, 1, 64);
  float r23 = v23 + w23;
  float vq = (l & 2) ? r23 : r01;
  float wq = __shfl_xor((l & 2) ? r01 : r23, 2, 64);
  float rr = vq + wq;
  rr += __shfl_xor(rr, 4, 64);
  rr += __shfl_xor(rr, 8, 64);
  rr += __shfl_xor(rr, 16, 64);
  float* outp = half ? r : p;
  if (dpos < 4) outp[(size_t)wid * 4 + dpos] = rr;
}

// ---------------- layer-2 aggregation + final linear --------------------
// 8 lanes per node: lanes gather 8 edges in parallel (csr reads 32B
// contiguous per group), multi-value butterfly reduces all 4 dims, then a
// 2-shfl projection produces both outputs. 3125 blocks (vs 391 before).
__global__ __launch_bounds__(256) void k_final(
    const float* __restrict__ p, const float* __restrict__ r,
    const int* __restrict__ csr, const int* __restrict__ off,
    const int* __restrict__ deg,
    const float* __restrict__ b2,
    const float* __restrict__ Wlin, const float* __restrict__ blin,
    float* __restrict__ out) {
  int gid = blockIdx.x * blockDim.x + threadIdx.x;
  int node = gid >> 3;
  int sl = gid & 7;
  if (node >= NN) return;
  int cnt = deg[node], st = off[node];
  int l = threadIdx.x & 63;

  float a0 = 0.f, a1 = 0.f, a2 = 0.f, a3 = 0.f;
  for (int e = sl; e < cnt; e += 8) {
    int s = csr[st + e];
    const float4 pv = *(const float4*)(p + (size_t)s * 4);
    a0 += pv.x; a1 += pv.y; a2 += pv.z; a3 += pv.w;
  }
  // multi-value reduce within the 8-lane group
  float v01 = (l & 1) ? a1 : a0;
  float w01 = __shfl_xor((l & 1) ? a0 : a1, 1, 64);
  float r01 = v01 + w01;
  float v23 = (l & 1) ? a3 : a2;
  float w23 = __shfl_xor((l & 1) ? a2 : a3, 1, 64);
  float r23 = v23 + w23;
  float vq = (l & 2) ? r23 : r01;
  float wq = __shfl_xor((l & 2) ? r01 : r23, 2, 64);
  float rr = vq + wq;
  rr += __shfl_xor(rr, 4, 64);
  // lane (sl&3)==o holds agg_o over all 8 lanes
  int o = sl & 3;
  float inv = 1.f / (float)max(cnt, 1);
  float g = rr * inv + b2[o] + r[(size_t)node * 4 + o];
  // project onto Wlin rows: out0 = sum g_o*Wlin[o], out1 = sum g_o*Wlin[4+o]
  float t0 = g * Wlin[o];
  float t1 = g * Wlin[4 + o];
  float vv = (l & 1) ? t1 : t0;
  float ww = __shfl_xor((l & 1) ? t0 : t1, 1, 64);
  float q = vv + ww;
  q += __shfl_xor(q, 2, 64);
  if (sl < 2) out[(size_t)node * 2 + sl] = q + blin[sl];
}

// ---------------- launch ----------------

extern "C" void kernel_launch(void* const* d_in, const int* in_sizes, int n_in,
                              void* d_out, int out_size, void* d_ws, size_t ws_size,
                              hipStream_t stream) {
  const float* x    = (const float*)d_in[0];
  const int*   ei   = (const int*)d_in[1];
  const int*   src  = ei;
  const int*   dst  = ei + NE;
  const float* W1l  = (const float*)d_in[2];
  const float* b1   = (const float*)d_in[3];
  const float* W1r  = (const float*)d_in[4];
  const float* W2l  = (const float*)d_in[5];
  const float* b2   = (const float*)d_in[6];
  const float* W2r  = (const float*)d_in[7];
  const float* Wlin = (const float*)d_in[8];
  const float* blin = (const float*)d_in[9];
  float* out = (float*)d_out;

  char* w = (char*)d_ws;
  size_t o = 0;
  auto alloc = [&](size_t bytes) {
    void* pp = (void*)(w + o);
    o = (o + bytes + 255) & ~(size_t)255;
    return pp;
  };
  int* hist  = (int*)alloc(NBUK * 4);
  int* bbase = (int*)alloc(NBUK * 4);
  int* gcur  = (int*)alloc(NBUK * 4);
  unsigned int*  staged = (unsigned int*)alloc((size_t)NE * 4);
  int* csr   = (int*)alloc((size_t)NE * 4);
  int* offs  = (int*)alloc(NN * 4);
  int* deg   = (int*)alloc(NN * 4);
  unsigned short* Wcat  = (unsigned short*)alloc(256 * 128 * 2);
  unsigned short* ubuf  = (unsigned short*)alloc((size_t)NN * 128 * 2);
  unsigned short* vbuf  = (unsigned short*)alloc((size_t)NN * 128 * 2);
  float* pbuf = (float*)alloc((size_t)NN * 4 * 4);
  float* rbuf = (float*)alloc((size_t)NN * 4 * 4);

  const size_t scatter_lds = (size_t)EB * 4 + (size_t)EB * 2 + (size_t)4 * NBUK * 4;
  const size_t gemm1_lds = 256 * 272;   // 69632 B

  hipLaunchKernelGGL(k_zerob, dim3((NBUK + 255) / 256), dim3(256), 0, stream, hist);
  hipLaunchKernelGGL(k_hist,  dim3((NE + 16383) / 16384), dim3(256), 0, stream, dst, hist);
  hipLaunchKernelGGL(k_scanb, dim3(1), dim3(256), 0, stream, hist, bbase, gcur);
  hipLaunchKernelGGL(k_scatter, dim3((NE + EB - 1) / EB), dim3(256), scatter_lds, stream,
                     src, dst, gcur, staged);
  hipLaunchKernelGGL(k_sort2, dim3(NBUK), dim3(256), 0, stream,
                     staged, bbase, hist, csr, offs, deg);
  hipLaunchKernelGGL(k_packw, dim3(128), dim3(256), 0, stream, W1l, W1r, Wcat);
  hipLaunchKernelGGL(k_gemm1, dim3((NN + 63) / 64), dim3(256), gemm1_lds, stream,
                     x, Wcat, ubuf, vbuf);
  hipLaunchKernelGGL(k_agg,   dim3((NN * 64 + 255) / 256), dim3(256), 0, stream,
                     ubuf, vbuf, csr, offs, deg, b1, W2l, W2r, pbuf, rbuf);
  hipLaunchKernelGGL(k_final, dim3((NN * 8 + 255) / 256), dim3(256), 0, stream,
                     pbuf, rbuf, csr, offs, deg, b2, Wlin, blin, out);
}

// Round 8
// 276.292 us; speedup vs baseline: 1.3140x; 1.0169x over previous
//
#include <hip/hip_runtime.h>

#define NN 100000
#define NE 1600000
#define NBUK 1563          // ceil(NN/64) buckets of 64 nodes
#define EB 8192            // edges per scatter block

typedef __attribute__((ext_vector_type(8))) short v8s;
typedef __attribute__((ext_vector_type(4))) float v4f;

__device__ __forceinline__ unsigned short f2bf(float f) {
  unsigned int u = __float_as_uint(f);
  unsigned int r = (u + 0x7FFFu + ((u >> 16) & 1u)) >> 16;
  return (unsigned short)r;
}
__device__ __forceinline__ float bflo(unsigned int w) { return __uint_as_float(w << 16); }
__device__ __forceinline__ float bfhi(unsigned int w) { return __uint_as_float(w & 0xFFFF0000u); }
__device__ __forceinline__ float bf2f(unsigned short w) {
  return __uint_as_float((unsigned int)w << 16);
}

// ---------------- bucket histogram ----------------

__global__ void k_zerob(int* __restrict__ hist) {
  int i = blockIdx.x * blockDim.x + threadIdx.x;
  if (i < NBUK) hist[i] = 0;
}

__global__ __launch_bounds__(256) void k_hist(const int* __restrict__ dst,
                                              int* __restrict__ hist) {
  __shared__ int lh[NBUK];
  int t = threadIdx.x;
  for (int i = t; i < NBUK; i += 256) lh[i] = 0;
  __syncthreads();
  int base = blockIdx.x * 16384;
  int lim = min(16384, NE - base);
  for (int j = t; j < lim; j += 256) atomicAdd(&lh[dst[base + j] >> 6], 1);
  __syncthreads();
  for (int i = t; i < NBUK; i += 256) {
    int c = lh[i];
    if (c) atomicAdd(&hist[i], c);
  }
}

// single-block exclusive scan: hist -> bbase, gcur (shfl-based, 2 barriers/chunk)
__global__ __launch_bounds__(256) void k_scanb(const int* __restrict__ hist,
                                               int* __restrict__ bbase,
                                               int* __restrict__ gcur) {
  __shared__ int wsum[4];
  int t = threadIdx.x, w = t >> 6, l = t & 63;
  int carry = 0;
  for (int c = 0; c < (NBUK + 255) / 256; ++c) {
    int i = c * 256 + t;
    int vv = (i < NBUK) ? hist[i] : 0;
    int inc = vv;
#pragma unroll
    for (int o = 1; o < 64; o <<= 1) {
      int uu = __shfl_up(inc, o, 64);
      if (l >= o) inc += uu;
    }
    if (l == 63) wsum[w] = inc;
    __syncthreads();
    int woff = 0;
    for (int j = 0; j < w; ++j) woff += wsum[j];
    int excl = carry + woff + inc - vv;
    if (i < NBUK) { bbase[i] = excl; gcur[i] = excl; }
    int tot = wsum[0] + wsum[1] + wsum[2] + wsum[3];
    __syncthreads();
    carry += tot;
  }
}

// ---------------- bucket scatter (no per-block scan, direct claimed writes) -
// staged[k] = (src<<6) | dstLocal, grouped per bucket (order within bucket
// arbitrary). Per block: LDS hist -> one global claim per bucket -> direct
// global scatter into the claimed window.
__global__ __launch_bounds__(256) void k_scatter(const int* __restrict__ src,
                                                 const int* __restrict__ dst,
                                                 int* __restrict__ gcur,
                                                 unsigned int* __restrict__ staged) {
  __shared__ int lhist[NBUK];
  __shared__ int lcur[NBUK];
  __shared__ int gclaim[NBUK];
  int t = threadIdx.x;
  int e0 = blockIdx.x * EB;
  int ecnt = min(EB, NE - e0);
  for (int i = t; i < NBUK; i += 256) { lhist[i] = 0; lcur[i] = 0; }
  __syncthreads();
  for (int j = t; j < ecnt; j += 256) atomicAdd(&lhist[dst[e0 + j] >> 6], 1);
  __syncthreads();
  for (int b = t; b < NBUK; b += 256) {
    int c = lhist[b];
    gclaim[b] = c ? atomicAdd(&gcur[b], c) : 0;
  }
  __syncthreads();
  for (int j = t; j < ecnt; j += 256) {
    int s = src[e0 + j], d = dst[e0 + j];
    int b = d >> 6;
    int lp = atomicAdd(&lcur[b], 1);
    staged[gclaim[b] + lp] = ((unsigned int)s << 6) | (unsigned int)(d & 63);
  }
}

// ---------------- per-bucket radix pass 2: staged -> CSR + off + deg -------
__global__ __launch_bounds__(256) void k_sort2(const unsigned int* __restrict__ staged,
                                               const int* __restrict__ bbase,
                                               const int* __restrict__ hist,
                                               int* __restrict__ csr,
                                               int* __restrict__ off,
                                               int* __restrict__ deg) {
  __shared__ int h64[64], c64[64];
  int bkt = blockIdx.x, t = threadIdx.x;
  if (t < 64) h64[t] = 0;
  __syncthreads();
  int st = bbase[bkt], cnt = hist[bkt];
  for (int j = t; j < cnt; j += 256) atomicAdd(&h64[staged[st + j] & 63], 1);
  __syncthreads();
  if (t < 64) {
    int v = h64[t];
    int inc = v;
    for (int o = 1; o < 64; o <<= 1) {
      int uu = __shfl_up(inc, o, 64);
      if (t >= o) inc += uu;
    }
    int excl = inc - v;
    c64[t] = excl;
    int node = bkt * 64 + t;
    if (node < NN) { off[node] = st + excl; deg[node] = v; }
  }
  __syncthreads();
  for (int j = t; j < cnt; j += 256) {
    unsigned pk = staged[st + j];
    int lp = atomicAdd(&c64[pk & 63], 1);
    csr[st + lp] = (int)(pk >> 6);
  }
}

// ---------------- weight pack ----------------

__global__ void k_packw(const float* __restrict__ W1l, const float* __restrict__ W1r,
                        unsigned short* __restrict__ Wcat) {
  int i = blockIdx.x * blockDim.x + threadIdx.x;  // 0..32767
  float f = (i < 16384) ? W1l[i] : W1r[i - 16384];
  Wcat[i] = f2bf(f);
}

// ---------------- MFMA GEMM: u = x@W1l^T, v = x@W1r^T (bf16 out) ----------
// W staged in LDS (pitch 272B); operands swapped (A=W, B=x) so each lane
// owns 4 consecutive output cols of one x-row -> 8B uint2 stores.
extern __shared__ char smem_dyn[];
__global__ __launch_bounds__(256) void k_gemm1(
    const float* __restrict__ x, const unsigned short* __restrict__ Wcat,
    unsigned short* __restrict__ u, unsigned short* __restrict__ v) {
  char* wlds = smem_dyn;
  int t = threadIdx.x;
  {
    int rsub = t >> 4, chunk = t & 15;
#pragma unroll
    for (int rd = 0; rd < 16; ++rd) {
      int row = rd * 16 + rsub;
      uint4 w4 = *(const uint4*)(Wcat + (size_t)row * 128 + chunk * 8);
      *(uint4*)(wlds + row * 272 + chunk * 16) = w4;
    }
  }

  int wave = t >> 6, l = t & 63;
  int m0 = blockIdx.x * 64 + wave * 16;
  int lr = l & 15, kq = l >> 4;
  int rowc = min(m0 + lr, NN - 1);

  v8s a[4];
#pragma unroll
  for (int ks = 0; ks < 4; ++ks) {
    const float* xp = x + (size_t)rowc * 128 + ks * 32 + kq * 8;
    float4 f0 = *(const float4*)xp;
    float4 f1 = *(const float4*)(xp + 4);
    v8s tv;
    tv[0] = (short)f2bf(f0.x); tv[1] = (short)f2bf(f0.y);
    tv[2] = (short)f2bf(f0.z); tv[3] = (short)f2bf(f0.w);
    tv[4] = (short)f2bf(f1.x); tv[5] = (short)f2bf(f1.y);
    tv[6] = (short)f2bf(f1.z); tv[7] = (short)f2bf(f1.w);
    a[ks] = tv;
  }

  __syncthreads();

  v4f acc[16];
#pragma unroll
  for (int nt = 0; nt < 16; ++nt) acc[nt] = (v4f){0.f, 0.f, 0.f, 0.f};

#pragma unroll
  for (int nt = 0; nt < 16; ++nt) {
    const char* wrow = wlds + (nt * 16 + lr) * 272;
#pragma unroll
    for (int ks = 0; ks < 4; ++ks) {
      v8s b = *(const v8s*)(wrow + ks * 64 + kq * 16);
      acc[nt] = __builtin_amdgcn_mfma_f32_16x16x32_bf16(b, a[ks], acc[nt], 0, 0, 0);
    }
  }

  if (m0 + lr < NN) {
    size_t rowb = (size_t)(m0 + lr) * 128;
#pragma unroll
    for (int nt = 0; nt < 16; ++nt) {
      unsigned lo = (unsigned)f2bf(acc[nt][0]) | ((unsigned)f2bf(acc[nt][1]) << 16);
      unsigned hi = (unsigned)f2bf(acc[nt][2]) | ((unsigned)f2bf(acc[nt][3]) << 16);
      int col = (nt & 7) * 16 + kq * 4;
      if (nt < 8) *(uint2*)(u + rowb + col) = make_uint2(lo, hi);
      else        *(uint2*)(v + rowb + col) = make_uint2(lo, hi);
    }
  }
}

// ---------------- fused: mean-agg(u) + v + b1 -> relu -> h1; p=h1@W2l^T,
//                  r=h1@W2r^T.
// One wave per node, QUAD layout: quarter = l>>4 picks edge of a quad,
// dp = l&15 covers dims 8*dp..+7 via one dwordx4 (8 bf16). Wave processes
// 4 edges per load instruction. Quarter q computes outputs q*2, q*2+1 of
// [p0..3, r0..3] in the epilogue (4-stage intra-quarter butterfly).
__global__ __launch_bounds__(256) void k_agg(
    const unsigned short* __restrict__ u, const unsigned short* __restrict__ v,
    const int* __restrict__ csr, const int* __restrict__ off, const int* __restrict__ deg,
    const float* __restrict__ b1,
    const float* __restrict__ W2l, const float* __restrict__ W2r,
    float* __restrict__ p, float* __restrict__ r) {
  int wid = (blockIdx.x * blockDim.x + threadIdx.x) >> 6;  // node
  int l = threadIdx.x & 63;
  if (wid >= NN) return;
  int cnt = deg[wid], st = off[wid];
  int quarter = l >> 4;
  int dp = l & 15;
  const char* ubase = (const char*)u + (dp << 4);

  // hoisted epilogue operands (overlap with gather latency)
  uint4 vw = *(const uint4*)((const char*)v + ((size_t)wid << 8) + (dp << 4));
  float4 bbA = *(const float4*)(b1 + 8 * dp);
  float4 bbB = *(const float4*)(b1 + 8 * dp + 4);
  int obase = quarter * 2;  // 0,2 -> p rows 0..3 ; 4,6 -> r rows 0..3
  const float* WrowLo = (obase < 4) ? (W2l + obase * 128) : (W2r + (obase - 4) * 128);
  const float* WrowHi = WrowLo + 128;
  float4 wl0 = *(const float4*)(WrowLo + 8 * dp);
  float4 wl1 = *(const float4*)(WrowLo + 8 * dp + 4);
  float4 wh0 = *(const float4*)(WrowHi + 8 * dp);
  float4 wh1 = *(const float4*)(WrowHi + 8 * dp + 4);

  float a0 = 0.f, a1 = 0.f, a2 = 0.f, a3 = 0.f;
  float a4 = 0.f, a5 = 0.f, a6 = 0.f, a7 = 0.f;

#define LOADQ(W, S) uint4 W = *(const uint4*)(ubase + ((size_t)((unsigned)(S) << 8)))
#define ACCQ(W) { a0 += bflo(W.x); a1 += bfhi(W.x); a2 += bflo(W.y); a3 += bfhi(W.y); \
                  a4 += bflo(W.z); a5 += bfhi(W.z); a6 += bflo(W.w); a7 += bfhi(W.w); }

  for (int base = 0; base < cnt; base += 64) {
    int nloc = min(64, cnt - base);
    int idx = 0;
    if (l < nloc) idx = csr[st + base + l];
    int nquad = nloc >> 2;
    int e = 0;
    for (; e + 4 <= nquad; e += 4) {   // 16 edges in flight
      int s0 = __shfl(idx, 4 * e + quarter, 64);
      int s1 = __shfl(idx, 4 * (e + 1) + quarter, 64);
      int s2 = __shfl(idx, 4 * (e + 2) + quarter, 64);
      int s3 = __shfl(idx, 4 * (e + 3) + quarter, 64);
      LOADQ(w0, s0);
      LOADQ(w1, s1);
      LOADQ(w2, s2);
      LOADQ(w3, s3);
      ACCQ(w0); ACCQ(w1); ACCQ(w2); ACCQ(w3);
    }
    for (; e < nquad; ++e) {
      int s = __shfl(idx, 4 * e + quarter, 64);
      LOADQ(w, s);
      ACCQ(w);
    }
    int rem = nloc & 3;
    if (rem) {
      int s = __shfl(idx, (nquad << 2) + quarter, 64);
      if (quarter < rem) {
        LOADQ(w, s);
        ACCQ(w);
      }
    }
  }
#undef LOADQ
#undef ACCQ

  // merge the four quarters; afterwards every lane holds full sums
  a0 += __shfl_xor(a0, 16, 64); a0 += __shfl_xor(a0, 32, 64);
  a1 += __shfl_xor(a1, 16, 64); a1 += __shfl_xor(a1, 32, 64);
  a2 += __shfl_xor(a2, 16, 64); a2 += __shfl_xor(a2, 32, 64);
  a3 += __shfl_xor(a3, 16, 64); a3 += __shfl_xor(a3, 32, 64);
  a4 += __shfl_xor(a4, 16, 64); a4 += __shfl_xor(a4, 32, 64);
  a5 += __shfl_xor(a5, 16, 64); a5 += __shfl_xor(a5, 32, 64);
  a6 += __shfl_xor(a6, 16, 64); a6 += __shfl_xor(a6, 32, 64);
  a7 += __shfl_xor(a7, 16, 64); a7 += __shfl_xor(a7, 32, 64);

  float inv = 1.f / (float)max(cnt, 1);
  float h0 = fmaxf(fmaf(a0, inv, bflo(vw.x) + bbA.x), 0.f);
  float h1 = fmaxf(fmaf(a1, inv, bfhi(vw.x) + bbA.y), 0.f);
  float h2 = fmaxf(fmaf(a2, inv, bflo(vw.y) + bbA.z), 0.f);
  float h3 = fmaxf(fmaf(a3, inv, bfhi(vw.y) + bbA.w), 0.f);
  float h4 = fmaxf(fmaf(a4, inv, bflo(vw.z) + bbB.x), 0.f);
  float h5 = fmaxf(fmaf(a5, inv, bfhi(vw.z) + bbB.y), 0.f);
  float h6 = fmaxf(fmaf(a6, inv, bflo(vw.w) + bbB.z), 0.f);
  float h7 = fmaxf(fmaf(a7, inv, bfhi(vw.w) + bbB.w), 0.f);

  // quarter q -> outputs obase, obase+1 ; multi-value butterfly in 16 lanes
  float tlo = h0 * wl0.x + h1 * wl0.y + h2 * wl0.z + h3 * wl0.w +
              h4 * wl1.x + h5 * wl1.y + h6 * wl1.z + h7 * wl1.w;
  float thi = h0 * wh0.x + h1 * wh0.y + h2 * wh0.z + h3 * wh0.w +
              h4 * wh1.x + h5 * wh1.y + h6 * wh1.z + h7 * wh1.w;
  float vsel = (l & 1) ? thi : tlo;
  float wsel = __shfl_xor((l & 1) ? tlo : thi, 1, 64);
  float s = vsel + wsel;     // lane holds output obase + (l&1), pair-summed
  s += __shfl_xor(s, 2, 64);
  s += __shfl_xor(s, 4, 64);
  s += __shfl_xor(s, 8, 64);
  if (dp < 2) {              // dp==0 -> obase, dp==1 -> obase+1
    int oo = obase + (l & 1);
    if (oo < 4) p[(size_t)wid * 4 + oo] = s;
    else        r[(size_t)wid * 4 + (oo - 4)] = s;
  }
}

// ---------------- layer-2 aggregation + final linear --------------------
__global__ __launch_bounds__(256) void k_final(
    const float* __restrict__ p, const float* __restrict__ r,
    const int* __restrict__ csr, const int* __restrict__ off,
    const int* __restrict__ deg,
    const float* __restrict__ b2,
    const float* __restrict__ Wlin, const float* __restrict__ blin,
    float* __restrict__ out) {
  int gid = blockIdx.x * blockDim.x + threadIdx.x;
  int node = gid >> 3;
  int sl = gid & 7;
  if (node >= NN) return;
  int cnt = deg[node], st = off[node];
  int l = threadIdx.x & 63;

  float a0 = 0.f, a1 = 0.f, a2 = 0.f, a3 = 0.f;
  for (int e = sl; e < cnt; e += 8) {
    int s = csr[st + e];
    const float4 pv = *(const float4*)(p + (size_t)s * 4);
    a0 += pv.x; a1 += pv.y; a2 += pv.z; a3 += pv.w;
  }
  float v01 = (l & 1) ? a1 : a0;
  float w01 = __shfl_xor((l & 1) ? a0 : a1, 1, 64);
  float r01 = v01 + w01;
  float v23 = (l & 1) ? a3 : a2;
  float w23 = __shfl_xor((l & 1) ? a2 : a3, 1, 64);
  float r23 = v23 + w23;
  float vq = (l & 2) ? r23 : r01;
  float wq = __shfl_xor((l & 2) ? r01 : r23, 2, 64);
  float rr = vq + wq;
  rr += __shfl_xor(rr, 4, 64);
  int o = sl & 3;
  float inv = 1.f / (float)max(cnt, 1);
  float g = rr * inv + b2[o] + r[(size_t)node * 4 + o];
  float t0 = g * Wlin[o];
  float t1 = g * Wlin[4 + o];
  float vv = (l & 1) ? t1 : t0;
  float ww = __shfl_xor((l & 1) ? t0 : t1, 1, 64);
  float q = vv + ww;
  q += __shfl_xor(q, 2, 64);
  if (sl < 2) out[(size_t)node * 2 + sl] = q + blin[sl];
}

// ---------------- launch ----------------

extern "C" void kernel_launch(void* const* d_in, const int* in_sizes, int n_in,
                              void* d_out, int out_size, void* d_ws, size_t ws_size,
                              hipStream_t stream) {
  const float* x    = (const float*)d_in[0];
  const int*   ei   = (const int*)d_in[1];
  const int*   src  = ei;
  const int*   dst  = ei + NE;
  const float* W1l  = (const float*)d_in[2];
  const float* b1   = (const float*)d_in[3];
  const float* W1r  = (const float*)d_in[4];
  const float* W2l  = (const float*)d_in[5];
  const float* b2   = (const float*)d_in[6];
  const float* W2r  = (const float*)d_in[7];
  const float* Wlin = (const float*)d_in[8];
  const float* blin = (const float*)d_in[9];
  float* out = (float*)d_out;

  char* w = (char*)d_ws;
  size_t o = 0;
  auto alloc = [&](size_t bytes) {
    void* pp = (void*)(w + o);
    o = (o + bytes + 255) & ~(size_t)255;
    return pp;
  };
  int* hist  = (int*)alloc(NBUK * 4);
  int* bbase = (int*)alloc(NBUK * 4);
  int* gcur  = (int*)alloc(NBUK * 4);
  unsigned int*  staged = (unsigned int*)alloc((size_t)NE * 4);
  int* csr   = (int*)alloc((size_t)NE * 4);
  int* offs  = (int*)alloc(NN * 4);
  int* deg   = (int*)alloc(NN * 4);
  unsigned short* Wcat  = (unsigned short*)alloc(256 * 128 * 2);
  unsigned short* ubuf  = (unsigned short*)alloc((size_t)NN * 128 * 2);
  unsigned short* vbuf  = (unsigned short*)alloc((size_t)NN * 128 * 2);
  float* pbuf = (float*)alloc((size_t)NN * 4 * 4);
  float* rbuf = (float*)alloc((size_t)NN * 4 * 4);

  const size_t gemm1_lds = 256 * 272;   // 69632 B

  hipLaunchKernelGGL(k_zerob, dim3((NBUK + 255) / 256), dim3(256), 0, stream, hist);
  hipLaunchKernelGGL(k_hist,  dim3((NE + 16383) / 16384), dim3(256), 0, stream, dst, hist);
  hipLaunchKernelGGL(k_scanb, dim3(1), dim3(256), 0, stream, hist, bbase, gcur);
  hipLaunchKernelGGL(k_scatter, dim3((NE + EB - 1) / EB), dim3(256), 0, stream,
                     src, dst, gcur, staged);
  hipLaunchKernelGGL(k_sort2, dim3(NBUK), dim3(256), 0, stream,
                     staged, bbase, hist, csr, offs, deg);
  hipLaunchKernelGGL(k_packw, dim3(128), dim3(256), 0, stream, W1l, W1r, Wcat);
  hipLaunchKernelGGL(k_gemm1, dim3((NN + 63) / 64), dim3(256), gemm1_lds, stream,
                     x, Wcat, ubuf, vbuf);
  hipLaunchKernelGGL(k_agg,   dim3((NN * 64 + 255) / 256), dim3(256), 0, stream,
                     ubuf, vbuf, csr, offs, deg, b1, W2l, W2r, pbuf, rbuf);
  hipLaunchKernelGGL(k_final, dim3((NN * 8 + 255) / 256), dim3(256), 0, stream,
                     pbuf, rbuf, csr, offs, deg, b2, Wlin, blin, out);
}

// Round 9
// 269.156 us; speedup vs baseline: 1.3488x; 1.0265x over previous
//
#include <hip/hip_runtime.h>

#define NN 100000
#define NE 1600000
#define NBUK 1563          // ceil(NN/64) buckets of 64 nodes
#define EB 8192            // edges per scatter block

typedef __attribute__((ext_vector_type(8))) short v8s;
typedef __attribute__((ext_vector_type(4))) float v4f;

__device__ __forceinline__ unsigned short f2bf(float f) {
  unsigned int u = __float_as_uint(f);
  unsigned int r = (u + 0x7FFFu + ((u >> 16) & 1u)) >> 16;
  return (unsigned short)r;
}
__device__ __forceinline__ float bflo(unsigned int w) { return __uint_as_float(w << 16); }
__device__ __forceinline__ float bfhi(unsigned int w) { return __uint_as_float(w & 0xFFFF0000u); }
__device__ __forceinline__ float bf2f(unsigned short w) {
  return __uint_as_float((unsigned int)w << 16);
}

// ---------------- bucket histogram ----------------

__global__ void k_zerob(int* __restrict__ hist) {
  int i = blockIdx.x * blockDim.x + threadIdx.x;
  if (i < NBUK) hist[i] = 0;
}

// 391 blocks (4096 edges each) -- 98 blocks left 62% of CUs idle
__global__ __launch_bounds__(256) void k_hist(const int* __restrict__ dst,
                                              int* __restrict__ hist) {
  __shared__ int lh[NBUK];
  int t = threadIdx.x;
  for (int i = t; i < NBUK; i += 256) lh[i] = 0;
  __syncthreads();
  int base = blockIdx.x * 4096;
  int lim = min(4096, NE - base);
  for (int j = t; j < lim; j += 256) atomicAdd(&lh[dst[base + j] >> 6], 1);
  __syncthreads();
  for (int i = t; i < NBUK; i += 256) {
    int c = lh[i];
    if (c) atomicAdd(&hist[i], c);
  }
}

// single-block exclusive scan: hist -> bbase, gcur (shfl-based, 2 barriers/chunk)
__global__ __launch_bounds__(256) void k_scanb(const int* __restrict__ hist,
                                               int* __restrict__ bbase,
                                               int* __restrict__ gcur) {
  __shared__ int wsum[4];
  int t = threadIdx.x, w = t >> 6, l = t & 63;
  int carry = 0;
  for (int c = 0; c < (NBUK + 255) / 256; ++c) {
    int i = c * 256 + t;
    int vv = (i < NBUK) ? hist[i] : 0;
    int inc = vv;
#pragma unroll
    for (int o = 1; o < 64; o <<= 1) {
      int uu = __shfl_up(inc, o, 64);
      if (l >= o) inc += uu;
    }
    if (l == 63) wsum[w] = inc;
    __syncthreads();
    int woff = 0;
    for (int j = 0; j < w; ++j) woff += wsum[j];
    int excl = carry + woff + inc - vv;
    if (i < NBUK) { bbase[i] = excl; gcur[i] = excl; }
    int tot = wsum[0] + wsum[1] + wsum[2] + wsum[3];
    __syncthreads();
    carry += tot;
  }
}

// ---------------- bucket scatter (direct claimed writes) -------------------
__global__ __launch_bounds__(256) void k_scatter(const int* __restrict__ src,
                                                 const int* __restrict__ dst,
                                                 int* __restrict__ gcur,
                                                 unsigned int* __restrict__ staged) {
  __shared__ int lhist[NBUK];
  __shared__ int lcur[NBUK];
  __shared__ int gclaim[NBUK];
  int t = threadIdx.x;
  int e0 = blockIdx.x * EB;
  int ecnt = min(EB, NE - e0);
  for (int i = t; i < NBUK; i += 256) { lhist[i] = 0; lcur[i] = 0; }
  __syncthreads();
  for (int j = t; j < ecnt; j += 256) atomicAdd(&lhist[dst[e0 + j] >> 6], 1);
  __syncthreads();
  for (int b = t; b < NBUK; b += 256) {
    int c = lhist[b];
    gclaim[b] = c ? atomicAdd(&gcur[b], c) : 0;
  }
  __syncthreads();
  for (int j = t; j < ecnt; j += 256) {
    int s = src[e0 + j], d = dst[e0 + j];
    int b = d >> 6;
    int lp = atomicAdd(&lcur[b], 1);
    staged[gclaim[b] + lp] = ((unsigned int)s << 6) | (unsigned int)(d & 63);
  }
}

// ---------------- per-bucket radix pass 2: staged -> CSR + off + deg -------
__global__ __launch_bounds__(256) void k_sort2(const unsigned int* __restrict__ staged,
                                               const int* __restrict__ bbase,
                                               const int* __restrict__ hist,
                                               int* __restrict__ csr,
                                               int* __restrict__ off,
                                               int* __restrict__ deg) {
  __shared__ int h64[64], c64[64];
  int bkt = blockIdx.x, t = threadIdx.x;
  if (t < 64) h64[t] = 0;
  __syncthreads();
  int st = bbase[bkt], cnt = hist[bkt];
  for (int j = t; j < cnt; j += 256) atomicAdd(&h64[staged[st + j] & 63], 1);
  __syncthreads();
  if (t < 64) {
    int v = h64[t];
    int inc = v;
    for (int o = 1; o < 64; o <<= 1) {
      int uu = __shfl_up(inc, o, 64);
      if (t >= o) inc += uu;
    }
    int excl = inc - v;
    c64[t] = excl;
    int node = bkt * 64 + t;
    if (node < NN) { off[node] = st + excl; deg[node] = v; }
  }
  __syncthreads();
  for (int j = t; j < cnt; j += 256) {
    unsigned pk = staged[st + j];
    int lp = atomicAdd(&c64[pk & 63], 1);
    csr[st + lp] = (int)(pk >> 6);
  }
}

// ---------------- MFMA GEMM: u = x@W1l^T, v = x@W1r^T (bf16 out) ----------
// v3: 512-thread blocks, 128 rows/block -> 16 waves/CU (4/SIMD) at the same
// 69.6KB LDS (2 blocks/CU); W staged+converted f32->bf16 in one pass
// (k_packw folded in). Operands swapped (A=W, B=x): lane owns 4 consecutive
// output cols of one x-row -> 8B uint2 stores.
extern __shared__ char smem_dyn[];
__global__ __launch_bounds__(512) void k_gemm1(
    const float* __restrict__ x, const float* __restrict__ W1l,
    const float* __restrict__ W1r,
    unsigned short* __restrict__ u, unsigned short* __restrict__ v) {
  char* wlds = smem_dyn;
  int t = threadIdx.x;
  {
    int rsub = t >> 4, chunk = t & 15;   // rsub 0..31, chunk 0..15
#pragma unroll
    for (int rd = 0; rd < 8; ++rd) {
      int row = rd * 32 + rsub;
      const float* wsrc = (row < 128) ? (W1l + (size_t)row * 128 + chunk * 8)
                                      : (W1r + (size_t)(row - 128) * 128 + chunk * 8);
      float4 f0 = *(const float4*)wsrc;
      float4 f1 = *(const float4*)(wsrc + 4);
      unsigned d0 = (unsigned)f2bf(f0.x) | ((unsigned)f2bf(f0.y) << 16);
      unsigned d1 = (unsigned)f2bf(f0.z) | ((unsigned)f2bf(f0.w) << 16);
      unsigned d2 = (unsigned)f2bf(f1.x) | ((unsigned)f2bf(f1.y) << 16);
      unsigned d3 = (unsigned)f2bf(f1.z) | ((unsigned)f2bf(f1.w) << 16);
      *(uint4*)(wlds + row * 272 + chunk * 16) = make_uint4(d0, d1, d2, d3);
    }
  }

  int wave = t >> 6, l = t & 63;
  int m0 = blockIdx.x * 128 + wave * 16;
  int lr = l & 15, kq = l >> 4;
  int rowc = min(m0 + lr, NN - 1);

  v8s a[4];
#pragma unroll
  for (int ks = 0; ks < 4; ++ks) {
    const float* xp = x + (size_t)rowc * 128 + ks * 32 + kq * 8;
    float4 f0 = *(const float4*)xp;
    float4 f1 = *(const float4*)(xp + 4);
    v8s tv;
    tv[0] = (short)f2bf(f0.x); tv[1] = (short)f2bf(f0.y);
    tv[2] = (short)f2bf(f0.z); tv[3] = (short)f2bf(f0.w);
    tv[4] = (short)f2bf(f1.x); tv[5] = (short)f2bf(f1.y);
    tv[6] = (short)f2bf(f1.z); tv[7] = (short)f2bf(f1.w);
    a[ks] = tv;
  }

  __syncthreads();

  v4f acc[16];
#pragma unroll
  for (int nt = 0; nt < 16; ++nt) acc[nt] = (v4f){0.f, 0.f, 0.f, 0.f};

#pragma unroll
  for (int nt = 0; nt < 16; ++nt) {
    const char* wrow = wlds + (nt * 16 + lr) * 272;
#pragma unroll
    for (int ks = 0; ks < 4; ++ks) {
      v8s b = *(const v8s*)(wrow + ks * 64 + kq * 16);
      acc[nt] = __builtin_amdgcn_mfma_f32_16x16x32_bf16(b, a[ks], acc[nt], 0, 0, 0);
    }
  }

  if (m0 + lr < NN) {
    size_t rowb = (size_t)(m0 + lr) * 128;
#pragma unroll
    for (int nt = 0; nt < 16; ++nt) {
      unsigned lo = (unsigned)f2bf(acc[nt][0]) | ((unsigned)f2bf(acc[nt][1]) << 16);
      unsigned hi = (unsigned)f2bf(acc[nt][2]) | ((unsigned)f2bf(acc[nt][3]) << 16);
      int col = (nt & 7) * 16 + kq * 4;
      if (nt < 8) *(uint2*)(u + rowb + col) = make_uint2(lo, hi);
      else        *(uint2*)(v + rowb + col) = make_uint2(lo, hi);
    }
  }
}

// ---------------- fused: mean-agg(u) + v + b1 -> relu -> h1; p=h1@W2l^T,
//                  r=h1@W2r^T.  (reverted to the R6 pair-layout version:
// 40 VGPR / 54% occupancy measured 74.4us; quad layout regressed to 81)
__global__ __launch_bounds__(256) void k_agg(
    const unsigned short* __restrict__ u, const unsigned short* __restrict__ v,
    const int* __restrict__ csr, const int* __restrict__ off, const int* __restrict__ deg,
    const float* __restrict__ b1,
    const float* __restrict__ W2l, const float* __restrict__ W2r,
    float* __restrict__ p, float* __restrict__ r) {
  int wid = (blockIdx.x * blockDim.x + threadIdx.x) >> 6;  // node
  int l = threadIdx.x & 63;
  if (wid >= NN) return;
  int cnt = deg[wid], st = off[wid];
  int half = l >> 5;
  int dpos = l & 31;
  const char* ubase = (const char*)u + (dpos << 3);

  // hoisted epilogue operands (overlap with gather latency)
  uint2 vw = *(const uint2*)((const char*)v + ((size_t)wid << 8) + (dpos << 3));
  float4 bb = *(const float4*)(b1 + 4 * dpos);
  const float* Wbase = half ? W2r : W2l;
  float4 wv[4];
#pragma unroll
  for (int o = 0; o < 4; ++o) wv[o] = *(const float4*)(Wbase + o * 128 + 4 * dpos);

  float a0 = 0.f, a1 = 0.f, a2 = 0.f, a3 = 0.f;

#define LOADW(W, S) uint2 W = *(const uint2*)(ubase + ((size_t)((unsigned)(S) << 8)))
#define ACCW(W) { a0 += bflo(W.x); a1 += bfhi(W.x); a2 += bflo(W.y); a3 += bfhi(W.y); }

  for (int base = 0; base < cnt; base += 64) {
    int nloc = min(64, cnt - base);
    int idx = 0;
    if (l < nloc) idx = csr[st + base + l];
    int npair = nloc >> 1;
    int e = 0;
    for (; e + 8 <= npair; e += 8) {
      int s0 = __shfl(idx, 2 * e + half, 64);
      int s1 = __shfl(idx, 2 * (e + 1) + half, 64);
      int s2 = __shfl(idx, 2 * (e + 2) + half, 64);
      int s3 = __shfl(idx, 2 * (e + 3) + half, 64);
      int s4 = __shfl(idx, 2 * (e + 4) + half, 64);
      int s5 = __shfl(idx, 2 * (e + 5) + half, 64);
      int s6 = __shfl(idx, 2 * (e + 6) + half, 64);
      int s7 = __shfl(idx, 2 * (e + 7) + half, 64);
      LOADW(w0, s0);
      LOADW(w1, s1);
      LOADW(w2, s2);
      LOADW(w3, s3);
      LOADW(w4, s4);
      LOADW(w5, s5);
      LOADW(w6, s6);
      LOADW(w7, s7);
      ACCW(w0); ACCW(w1); ACCW(w2); ACCW(w3);
      ACCW(w4); ACCW(w5); ACCW(w6); ACCW(w7);
    }
    for (; e + 4 <= npair; e += 4) {
      int s0 = __shfl(idx, 2 * e + half, 64);
      int s1 = __shfl(idx, 2 * (e + 1) + half, 64);
      int s2 = __shfl(idx, 2 * (e + 2) + half, 64);
      int s3 = __shfl(idx, 2 * (e + 3) + half, 64);
      LOADW(w0, s0);
      LOADW(w1, s1);
      LOADW(w2, s2);
      LOADW(w3, s3);
      ACCW(w0); ACCW(w1); ACCW(w2); ACCW(w3);
    }
    for (; e < npair; ++e) {
      int s = __shfl(idx, 2 * e + half, 64);
      LOADW(w, s);
      ACCW(w);
    }
    if (nloc & 1) {
      int s = __shfl(idx, nloc - 1, 64);
      if (half == 0) {
        LOADW(w, s);
        ACCW(w);
      }
    }
  }
#undef LOADW
#undef ACCW

  // merge the two edge-halves; afterwards both halves hold full sums
  a0 += __shfl_xor(a0, 32, 64);
  a1 += __shfl_xor(a1, 32, 64);
  a2 += __shfl_xor(a2, 32, 64);
  a3 += __shfl_xor(a3, 32, 64);

  float inv = 1.f / (float)max(cnt, 1);
  float h0 = fmaxf(fmaf(a0, inv, bflo(vw.x) + bb.x), 0.f);
  float h1 = fmaxf(fmaf(a1, inv, bfhi(vw.x) + bb.y), 0.f);
  float h2 = fmaxf(fmaf(a2, inv, bflo(vw.y) + bb.z), 0.f);
  float h3 = fmaxf(fmaf(a3, inv, bfhi(vw.y) + bb.w), 0.f);

  // half 0 -> p = h@W2l^T ; half 1 -> r = h@W2r^T  (4 outputs each)
  float t0 = h0 * wv[0].x + h1 * wv[0].y + h2 * wv[0].z + h3 * wv[0].w;
  float t1 = h0 * wv[1].x + h1 * wv[1].y + h2 * wv[1].z + h3 * wv[1].w;
  float t2 = h0 * wv[2].x + h1 * wv[2].y + h2 * wv[2].z + h3 * wv[2].w;
  float t3 = h0 * wv[3].x + h1 * wv[3].y + h2 * wv[3].z + h3 * wv[3].w;
  // multi-value butterfly: after stage 2, lane (l&3)==o holds output o
  float v01 = (l & 1) ? t1 : t0;
  float w01 = __shfl_xor((l & 1) ? t0 : t1, 1, 64);
  float r01 = v01 + w01;
  float v23 = (l & 1) ? t3 : t2;
  float w23 = __shfl_xor((l & 1) ? t2 : t3, 1, 64);
  float r23 = v23 + w23;
  float vq = (l & 2) ? r23 : r01;
  float wq = __shfl_xor((l & 2) ? r01 : r23, 2, 64);
  float rr = vq + wq;
  rr += __shfl_xor(rr, 4, 64);
  rr += __shfl_xor(rr, 8, 64);
  rr += __shfl_xor(rr, 16, 64);
  float* outp = half ? r : p;
  if (dpos < 4) outp[(size_t)wid * 4 + dpos] = rr;
}

// ---------------- layer-2 aggregation + final linear --------------------
__global__ __launch_bounds__(256) void k_final(
    const float* __restrict__ p, const float* __restrict__ r,
    const int* __restrict__ csr, const int* __restrict__ off,
    const int* __restrict__ deg,
    const float* __restrict__ b2,
    const float* __restrict__ Wlin, const float* __restrict__ blin,
    float* __restrict__ out) {
  int gid = blockIdx.x * blockDim.x + threadIdx.x;
  int node = gid >> 3;
  int sl = gid & 7;
  if (node >= NN) return;
  int cnt = deg[node], st = off[node];
  int l = threadIdx.x & 63;

  float a0 = 0.f, a1 = 0.f, a2 = 0.f, a3 = 0.f;
  for (int e = sl; e < cnt; e += 8) {
    int s = csr[st + e];
    const float4 pv = *(const float4*)(p + (size_t)s * 4);
    a0 += pv.x; a1 += pv.y; a2 += pv.z; a3 += pv.w;
  }
  float v01 = (l & 1) ? a1 : a0;
  float w01 = __shfl_xor((l & 1) ? a0 : a1, 1, 64);
  float r01 = v01 + w01;
  float v23 = (l & 1) ? a3 : a2;
  float w23 = __shfl_xor((l & 1) ? a2 : a3, 1, 64);
  float r23 = v23 + w23;
  float vq = (l & 2) ? r23 : r01;
  float wq = __shfl_xor((l & 2) ? r01 : r23, 2, 64);
  float rr = vq + wq;
  rr += __shfl_xor(rr, 4, 64);
  int o = sl & 3;
  float inv = 1.f / (float)max(cnt, 1);
  float g = rr * inv + b2[o] + r[(size_t)node * 4 + o];
  float t0 = g * Wlin[o];
  float t1 = g * Wlin[4 + o];
  float vv = (l & 1) ? t1 : t0;
  float ww = __shfl_xor((l & 1) ? t0 : t1, 1, 64);
  float q = vv + ww;
  q += __shfl_xor(q, 2, 64);
  if (sl < 2) out[(size_t)node * 2 + sl] = q + blin[sl];
}

// ---------------- launch ----------------

extern "C" void kernel_launch(void* const* d_in, const int* in_sizes, int n_in,
                              void* d_out, int out_size, void* d_ws, size_t ws_size,
                              hipStream_t stream) {
  const float* x    = (const float*)d_in[0];
  const int*   ei   = (const int*)d_in[1];
  const int*   src  = ei;
  const int*   dst  = ei + NE;
  const float* W1l  = (const float*)d_in[2];
  const float* b1   = (const float*)d_in[3];
  const float* W1r  = (const float*)d_in[4];
  const float* W2l  = (const float*)d_in[5];
  const float* b2   = (const float*)d_in[6];
  const float* W2r  = (const float*)d_in[7];
  const float* Wlin = (const float*)d_in[8];
  const float* blin = (const float*)d_in[9];
  float* out = (float*)d_out;

  char* w = (char*)d_ws;
  size_t o = 0;
  auto alloc = [&](size_t bytes) {
    void* pp = (void*)(w + o);
    o = (o + bytes + 255) & ~(size_t)255;
    return pp;
  };
  int* hist  = (int*)alloc(NBUK * 4);
  int* bbase = (int*)alloc(NBUK * 4);
  int* gcur  = (int*)alloc(NBUK * 4);
  unsigned int*  staged = (unsigned int*)alloc((size_t)NE * 4);
  int* csr   = (int*)alloc((size_t)NE * 4);
  int* offs  = (int*)alloc(NN * 4);
  int* deg   = (int*)alloc(NN * 4);
  unsigned short* ubuf  = (unsigned short*)alloc((size_t)NN * 128 * 2);
  unsigned short* vbuf  = (unsigned short*)alloc((size_t)NN * 128 * 2);
  float* pbuf = (float*)alloc((size_t)NN * 4 * 4);
  float* rbuf = (float*)alloc((size_t)NN * 4 * 4);

  const size_t gemm1_lds = 256 * 272;   // 69632 B

  hipLaunchKernelGGL(k_zerob, dim3((NBUK + 255) / 256), dim3(256), 0, stream, hist);
  hipLaunchKernelGGL(k_hist,  dim3((NE + 4095) / 4096), dim3(256), 0, stream, dst, hist);
  hipLaunchKernelGGL(k_scanb, dim3(1), dim3(256), 0, stream, hist, bbase, gcur);
  hipLaunchKernelGGL(k_scatter, dim3((NE + EB - 1) / EB), dim3(256), 0, stream,
                     src, dst, gcur, staged);
  hipLaunchKernelGGL(k_sort2, dim3(NBUK), dim3(256), 0, stream,
                     staged, bbase, hist, csr, offs, deg);
  hipLaunchKernelGGL(k_gemm1, dim3((NN + 127) / 128), dim3(512), gemm1_lds, stream,
                     x, W1l, W1r, ubuf, vbuf);
  hipLaunchKernelGGL(k_agg,   dim3((NN * 64 + 255) / 256), dim3(256), 0, stream,
                     ubuf, vbuf, csr, offs, deg, b1, W2l, W2r, pbuf, rbuf);
  hipLaunchKernelGGL(k_final, dim3((NN * 8 + 255) / 256), dim3(256), 0, stream,
                     pbuf, rbuf, csr, offs, deg, b2, Wlin, blin, out);
}